// Round 6
// baseline (329.771 us; speedup 1.0000x reference)
//
#include <hip/hip_runtime.h>
#include <cmath>

typedef _Float16 f16;
typedef _Float16 f16x8 __attribute__((ext_vector_type(8)));
typedef _Float16 f16x4 __attribute__((ext_vector_type(4)));
typedef float f32x4 __attribute__((ext_vector_type(4)));

#define MFMA16(a, b, c) __builtin_amdgcn_mfma_f32_16x16x32_f16(a, b, c, 0, 0, 0)

static constexpr int Bsz = 4;
static constexpr int T = 2048;
static constexpr int V = 2048;
static constexpr int D = 256;
static constexpr int R = 512;
static constexpr int M = Bsz * T;   // 8192

// async global->LDS, 16B per lane; LDS dest = wave-uniform base + lane*16
__device__ __forceinline__ void load_lds16(const f16* g, f16* l) {
    __builtin_amdgcn_global_load_lds(
        (const __attribute__((address_space(1))) unsigned int*)(unsigned long long)g,
        (__attribute__((address_space(3))) unsigned int*)(unsigned int)(unsigned long long)l,
        16, 0, 0);
}

// ---------------------------------------------------------------- convert
__global__ __launch_bounds__(256) void conv_all(const float* __restrict__ s0,
                                                const float* __restrict__ s1,
                                                const float* __restrict__ s2,
                                                const float* __restrict__ s3,
                                                const float* __restrict__ s4,
                                                const float* __restrict__ s5,
                                                f16* __restrict__ dst) {
    int idx = (blockIdx.x * 256 + threadIdx.x) * 4;
    if (idx >= 4194304) return;
    const float* src; int off;
    if      (idx <  524288) { src = s0; off = idx; }
    else if (idx < 1048576) { src = s1; off = idx - 524288; }
    else if (idx < 1572864) { src = s2; off = idx - 1048576; }
    else if (idx < 2097152) { src = s3; off = idx - 1572864; }
    else if (idx < 3145728) { src = s4; off = idx - 2097152; }
    else                    { src = s5; off = idx - 3145728; }
    float4 v = *(const float4*)&src[off];
    f16x4 o;
    o[0] = (f16)v.x; o[1] = (f16)v.y; o[2] = (f16)v.z; o[3] = (f16)v.w;
    *(f16x4*)&dst[idx] = o;
}

// ---------------------------------------------------------------- rmsnorm (fp32 in)
__global__ __launch_bounds__(256) void rmsnorm_kernel(const float* __restrict__ x,
                                                      f16* __restrict__ out) {
    int row = blockIdx.x;
    const float* xr = x + (size_t)row * V;
    int tid = threadIdx.x;
    float4 v0 = ((const float4*)xr)[tid];
    float4 v1 = ((const float4*)xr)[tid + 256];
    float ss = v0.x * v0.x + v0.y * v0.y + v0.z * v0.z + v0.w * v0.w
             + v1.x * v1.x + v1.y * v1.y + v1.z * v1.z + v1.w * v1.w;
    #pragma unroll
    for (int o = 32; o > 0; o >>= 1) ss += __shfl_xor(ss, o);
    __shared__ float wsum[4];
    if ((tid & 63) == 0) wsum[tid >> 6] = ss;
    __syncthreads();
    float tot = wsum[0] + wsum[1] + wsum[2] + wsum[3];
    float s = rsqrtf(tot / (float)V + 1.1920929e-07f);
    f16* orow = out + (size_t)row * V;
    f16x4 o0, o1;
    o0[0] = (f16)(v0.x * s); o0[1] = (f16)(v0.y * s);
    o0[2] = (f16)(v0.z * s); o0[3] = (f16)(v0.w * s);
    o1[0] = (f16)(v1.x * s); o1[1] = (f16)(v1.y * s);
    o1[2] = (f16)(v1.z * s); o1[3] = (f16)(v1.w * s);
    *(f16x4*)&orow[tid * 4] = o0;
    *(f16x4*)&orow[1024 + tid * 4] = o1;
}

// ---------------------------------------------------------------- rmsnorm (f16 in)
__global__ __launch_bounds__(256) void rmsnorm_f16(const f16* __restrict__ x,
                                                   f16* __restrict__ out) {
    int row = blockIdx.x;
    int tid = threadIdx.x;
    const f16* xr = x + (size_t)row * V;
    f16x8 v = *(const f16x8*)&xr[tid * 8];
    float f[8];
    float ss = 0.f;
    #pragma unroll
    for (int j = 0; j < 8; j++) { f[j] = (float)v[j]; ss += f[j] * f[j]; }
    #pragma unroll
    for (int o = 32; o > 0; o >>= 1) ss += __shfl_xor(ss, o);
    __shared__ float wsum[4];
    if ((tid & 63) == 0) wsum[tid >> 6] = ss;
    __syncthreads();
    float tot = wsum[0] + wsum[1] + wsum[2] + wsum[3];
    float s = rsqrtf(tot / (float)V + 1.1920929e-07f);
    f16x8 o;
    #pragma unroll
    for (int j = 0; j < 8; j++) o[j] = (f16)(f[j] * s);
    *(f16x8*)&out[(size_t)row * V + tid * 8] = o;
}

// ---------------------------------------------------------------- GEMM epilogue params
struct GemmEpi {
    const float* residf;
    const f16* residh;
    float* outf;
    f16* outh;
    f16* out_q; f16* out_k; f16* out_vT;
    f16* out_h;
    const float* bias;
    const float* sA; const float* sB;
};

// Epilogue store for one 16-row fragment group (shared by all gemm kernels)
template <int MODE>
__device__ __forceinline__ void epi_store(const GemmEpi& e, float s, f32x4 a,
                                          int gm_base, int gn) {
    #pragma unroll
    for (int i = 0; i < 4; i++) {
        int gm = gm_base + i;
        float vv = a[i];
        if (MODE == 0) {
            if (gn < 256) {
                e.out_q[(size_t)gm * D + gn] = (f16)vv;
            } else if (gn < 512) {
                e.out_k[(size_t)gm * D + (gn - 256)] = (f16)vv;
            } else {
                int d = gn - 512;
                int b = gm >> 11, t = gm & 2047;
                e.out_vT[((size_t)b * D + d) * T + t] = (f16)vv;
            }
        } else if (MODE == 1) {
            size_t o = (size_t)gm * V + gn;
            e.outh[o] = (f16)(e.residf[o] + s * vv);
        } else if (MODE == 2) {
            float z = vv + e.bias[gn];
            float g = 0.5f * z * (1.f + erff(z * 0.70710678118654752f));
            e.out_h[(size_t)gm * R + gn] = (f16)g;
        } else {
            size_t o = (size_t)gm * V + gn;
            e.outf[o] = (float)e.residh[o] + s * vv;
        }
    }
}

// ---------------------------------------------------------------- GEMM NT 128x128 (grid-rich)
// C[m,n] = sum_k A[m,k]*B[n,k];  A: MxK row-major f16, B: NxK row-major f16
// 256 threads, 4 waves, 128x128 tile, double-buffered global_load_lds staging.
// Used for Wo (K=256) and Wup (K=512): grid 1024 blocks = 4/CU, 32 KiB LDS.
template <int MODE>
__global__ __launch_bounds__(256) void gemm_nt(const f16* __restrict__ A,
                                               const f16* __restrict__ Bm,
                                               int K, GemmEpi e) {
    __shared__ f16 Asl[2][128 * 32];
    __shared__ f16 Bsl[2][128 * 32];
    int tid = threadIdx.x;
    int lane = tid & 63, wv = tid >> 6;
    int wm = wv >> 1, wn = wv & 1;
    int quad = lane >> 4, l16 = lane & 15;
    int m0 = blockIdx.x * 128, n0 = blockIdx.y * 128;
    f32x4 acc[4][4] = {};

    int srow = lane >> 2;
    int scg = (lane & 3) ^ ((lane >> 3) & 3);
    const f16* Ag0 = &A[(size_t)(m0 + 16 * wv + srow) * K + scg * 8];
    const f16* Ag1 = &A[(size_t)(m0 + 16 * (wv + 4) + srow) * K + scg * 8];
    const f16* Bg0 = &Bm[(size_t)(n0 + 16 * wv + srow) * K + scg * 8];
    const f16* Bg1 = &Bm[(size_t)(n0 + 16 * (wv + 4) + srow) * K + scg * 8];
    int lo0 = (16 * wv) * 32, lo1 = (16 * (wv + 4)) * 32;

    int fs = quad ^ ((l16 >> 1) & 3);
    int niter = K >> 5;

    load_lds16(Ag0, &Asl[0][lo0]);
    load_lds16(Ag1, &Asl[0][lo1]);
    load_lds16(Bg0, &Bsl[0][lo0]);
    load_lds16(Bg1, &Bsl[0][lo1]);

    for (int i = 0; i < niter; i++) {
        int cur = i & 1;
        __builtin_amdgcn_s_barrier();
        if (i + 1 < niter) {
            int k0 = (i + 1) << 5;
            int nb = cur ^ 1;
            load_lds16(Ag0 + k0, &Asl[nb][lo0]);
            load_lds16(Ag1 + k0, &Asl[nb][lo1]);
            load_lds16(Bg0 + k0, &Bsl[nb][lo0]);
            load_lds16(Bg1 + k0, &Bsl[nb][lo1]);
            asm volatile("s_waitcnt vmcnt(4)" ::: "memory");
        } else {
            asm volatile("s_waitcnt vmcnt(0)" ::: "memory");
        }
        __builtin_amdgcn_s_barrier();
        f16x8 af[4], bf[4];
        #pragma unroll
        for (int j = 0; j < 4; j++)
            af[j] = *(const f16x8*)&Asl[cur][(64 * wm + 16 * j + l16) * 32 + fs * 8];
        #pragma unroll
        for (int j = 0; j < 4; j++)
            bf[j] = *(const f16x8*)&Bsl[cur][(64 * wn + 16 * j + l16) * 32 + fs * 8];
        #pragma unroll
        for (int mi = 0; mi < 4; mi++)
            #pragma unroll
            for (int ni = 0; ni < 4; ni++)
                acc[mi][ni] = MFMA16(af[mi], bf[ni], acc[mi][ni]);
    }

    float s = 0.f;
    if (MODE == 1 || MODE == 3) s = e.sA[0] * e.sB[0];
    #pragma unroll
    for (int mi = 0; mi < 4; mi++)
        #pragma unroll
        for (int ni = 0; ni < 4; ni++)
            epi_store<MODE>(e, s, acc[mi][ni],
                            m0 + 64 * wm + 16 * mi + quad * 4,
                            n0 + 64 * wn + 16 * ni + l16);
}

// ---------------------------------------------------------------- GEMM NT 64x128 (long-K)
// For the K=2048 GEMMs whose 128x128 grid is starved (QKV: 384 blk = 1.5/CU;
// Wdown: 256 blk = 1/CU). Co-residency theory (m97/m114): this exact 2-stage
// skeleton hits ~900TF only at >=3 blocks/CU, where co-resident blocks' waves
// overlap each other's barrier drains + ds_read latency. Halving the M-tile
// doubles the grid: QKV -> 768 blk = 3/CU, Wdown -> 512 blk = 2/CU.
// Per block: 4 waves, per-wave output 32x64 (acc[2][4], all-static indices),
// 3 staging loads/iter (1 A + 2 B, steady vmcnt(3)), 24 KiB LDS.
// Same XOR swizzle as gemm_nt: LDS[r][s] holds colgroup s^((r>>1)&3).
template <int MODE>
__global__ __launch_bounds__(256) void gemm_nt_64(const f16* __restrict__ A,
                                                  const f16* __restrict__ Bm,
                                                  int K, GemmEpi e) {
    __shared__ f16 Asl[2][64 * 32];
    __shared__ f16 Bsl[2][128 * 32];
    int tid = threadIdx.x;
    int lane = tid & 63, wv = tid >> 6;
    int wm = wv >> 1, wn = wv & 1;          // 2 (M) x 2 (N)
    int quad = lane >> 4, l16 = lane & 15;
    int m0 = blockIdx.x * 64, n0 = blockIdx.y * 128;
    f32x4 acc[2][4] = {};

    int srow = lane >> 2;
    int scg = (lane & 3) ^ ((lane >> 3) & 3);
    const f16* Ag0 = &A[(size_t)(m0 + 16 * wv + srow) * K + scg * 8];          // A rows 16wv..+15
    const f16* Bg0 = &Bm[(size_t)(n0 + 16 * wv + srow) * K + scg * 8];
    const f16* Bg1 = &Bm[(size_t)(n0 + 16 * (wv + 4) + srow) * K + scg * 8];
    int loA = (16 * wv) * 32;
    int lo0 = (16 * wv) * 32, lo1 = (16 * (wv + 4)) * 32;

    int fs = quad ^ ((l16 >> 1) & 3);
    int niter = K >> 5;

    load_lds16(Ag0, &Asl[0][loA]);
    load_lds16(Bg0, &Bsl[0][lo0]);
    load_lds16(Bg1, &Bsl[0][lo1]);

    for (int i = 0; i < niter; i++) {
        int cur = i & 1;
        __builtin_amdgcn_s_barrier();
        if (i + 1 < niter) {
            int k0 = (i + 1) << 5;
            int nb = cur ^ 1;
            load_lds16(Ag0 + k0, &Asl[nb][loA]);
            load_lds16(Bg0 + k0, &Bsl[nb][lo0]);
            load_lds16(Bg1 + k0, &Bsl[nb][lo1]);
            asm volatile("s_waitcnt vmcnt(3)" ::: "memory");
        } else {
            asm volatile("s_waitcnt vmcnt(0)" ::: "memory");
        }
        __builtin_amdgcn_s_barrier();
        f16x8 af[2], bf[4];
        #pragma unroll
        for (int j = 0; j < 2; j++)
            af[j] = *(const f16x8*)&Asl[cur][(32 * wm + 16 * j + l16) * 32 + fs * 8];
        #pragma unroll
        for (int j = 0; j < 4; j++)
            bf[j] = *(const f16x8*)&Bsl[cur][(64 * wn + 16 * j + l16) * 32 + fs * 8];
        #pragma unroll
        for (int mi = 0; mi < 2; mi++)
            #pragma unroll
            for (int ni = 0; ni < 4; ni++)
                acc[mi][ni] = MFMA16(af[mi], bf[ni], acc[mi][ni]);
    }

    float s = 0.f;
    if (MODE == 1 || MODE == 3) s = e.sA[0] * e.sB[0];
    #pragma unroll
    for (int mi = 0; mi < 2; mi++)
        #pragma unroll
        for (int ni = 0; ni < 4; ni++)
            epi_store<MODE>(e, s, acc[mi][ni],
                            m0 + 32 * wm + 16 * mi + quad * 4,
                            n0 + 64 * wn + 16 * ni + l16);
}

// ---------------------------------------------------------------- attention
// retrieved[t,d] = sum_{s>t} decay^(s-t-1) * (q_t . k_s) * v[s,d]
// grid: (T/32, B) = 256 blocks; block 256 (4 waves), QBLK=32.
// Waves split the s-axis (16 cols each) in QK^T and the d-axis (64 cols each)
// in PV. K read straight from L2 (no LDS stage; no cross-wave reuse, L2-fit).
// Decay-window truncation: tiles with max weight < 2^-25 contribute < ~1e-5.
__global__ __launch_bounds__(256) void attn_kernel(const f16* __restrict__ q,
                                                   const f16* __restrict__ k,
                                                   const f16* __restrict__ vT,
                                                   f16* __restrict__ ret,
                                                   const float* __restrict__ decay_logit) {
    __shared__ f16 Psl[32 * 72];
    int tid = threadIdx.x, lane = tid & 63, wv = tid >> 6;
    int quad = lane >> 4, l16 = lane & 15;
    int b = blockIdx.y, t0 = blockIdx.x * 32;
    const f16* qb = q + (size_t)b * T * D;
    const f16* kb = k + (size_t)b * T * D;
    const f16* vb = vT + (size_t)b * D * T;
    f16* rb = ret + (size_t)b * T * D;

    float dl = decay_logit[0];
    float decay = 1.f / (1.f + expf(-dl));
    float l2d = log2f(decay);
    float nl2d = -l2d;

    f16x8 qf[2][8];
    #pragma unroll
    for (int mi = 0; mi < 2; mi++)
        #pragma unroll
        for (int kk = 0; kk < 8; kk++)
            qf[mi][kk] = *(const f16x8*)&qb[(size_t)(t0 + 16 * mi + l16) * D + kk * 32 + quad * 8];

    f32x4 acc2[2][4] = {};

    for (int s0 = t0; s0 < T; s0 += 64) {
        if ((float)(s0 - t0 - 32) * nl2d > 25.f) break;
        int srow = s0 + 16 * wv + l16;
        int srcl = srow < T ? srow : T - 1;
        f32x4 sacc[2] = {};
        #pragma unroll
        for (int kk = 0; kk < 8; kk++) {
            f16x8 bf = *(const f16x8*)&kb[(size_t)srcl * D + kk * 32 + quad * 8];
            sacc[0] = MFMA16(qf[0][kk], bf, sacc[0]);
            sacc[1] = MFMA16(qf[1][kk], bf, sacc[1]);
        }
        __syncthreads();
        #pragma unroll
        for (int mi = 0; mi < 2; mi++) {
            #pragma unroll
            for (int i = 0; i < 4; i++) {
                int t_ = t0 + 16 * mi + quad * 4 + i;
                int diff = srow - t_;
                float w = (diff > 0 && srow < T) ? exp2f((float)(diff - 1) * l2d) : 0.f;
                Psl[(16 * mi + quad * 4 + i) * 72 + 16 * wv + l16] = (f16)(sacc[mi][i] * w);
            }
        }
        __syncthreads();
        #pragma unroll
        for (int kk = 0; kk < 2; kk++) {
            int sb = s0 + kk * 32 + quad * 8;
            if (sb >= T) sb = T - 8;
            f16x8 pa[2], vf[4];
            #pragma unroll
            for (int mi = 0; mi < 2; mi++)
                pa[mi] = *(const f16x8*)&Psl[(16 * mi + l16) * 72 + kk * 32 + quad * 8];
            #pragma unroll
            for (int ni = 0; ni < 4; ni++)
                vf[ni] = *(const f16x8*)&vb[(size_t)(64 * wv + 16 * ni + l16) * T + sb];
            #pragma unroll
            for (int mi = 0; mi < 2; mi++)
                #pragma unroll
                for (int ni = 0; ni < 4; ni++)
                    acc2[mi][ni] = MFMA16(pa[mi], vf[ni], acc2[mi][ni]);
        }
    }

    #pragma unroll
    for (int mi = 0; mi < 2; mi++) {
        #pragma unroll
        for (int ni = 0; ni < 4; ni++) {
            int t_ = t0 + 16 * mi + quad * 4;
            int d_ = 64 * wv + 16 * ni + l16;
            #pragma unroll
            for (int i = 0; i < 4; i++)
                rb[(size_t)(t_ + i) * D + d_] = (f16)acc2[mi][ni][i];
        }
    }
}

// ---------------------------------------------------------------- launch
extern "C" void kernel_launch(void* const* d_in, const int* in_sizes, int n_in,
                              void* d_out, int out_size, void* d_ws, size_t ws_size,
                              hipStream_t stream) {
    const float* x           = (const float*)d_in[0];
    const float* Wq          = (const float*)d_in[1];
    const float* Wk          = (const float*)d_in[2];
    const float* Wv          = (const float*)d_in[3];
    const float* Wo          = (const float*)d_in[4];
    const float* decay_logit = (const float*)d_in[5];
    const float* q_out_scale = (const float*)d_in[6];
    const float* Wdown       = (const float*)d_in[7];
    const float* Wup         = (const float*)d_in[8];
    const float* t_bias      = (const float*)d_in[9];
    const float* t_out_scale = (const float*)d_in[10];
    const float* q_scale     = (const float*)d_in[11];
    const float* t_scale     = (const float*)d_in[12];

    char* ws = (char*)d_ws;
    f16* Wqkv16  = (f16*)ws;  ws += (size_t)768 * V * 2;       // 3 MiB  } contiguous
    f16* Wo16    = (f16*)ws;  ws += (size_t)V * D * 2;         // 1 MiB  } dst for
    f16* Wdown16 = (f16*)ws;  ws += (size_t)R * V * 2;         // 2 MiB  } conv_all
    f16* Wup16   = (f16*)ws;  ws += (size_t)V * R * 2;         // 2 MiB  }
    f16* xn16    = (f16*)ws;  ws += (size_t)M * V * 2;         // 32 MiB (reused as xn2)
    f16* q16     = (f16*)ws;  ws += (size_t)M * D * 2;         // 4 MiB (reused by h16)
    f16* k16     = (f16*)ws;  ws += (size_t)M * D * 2;         // 4 MiB (reused by h16)
    f16* vT16    = (f16*)ws;  ws += (size_t)Bsz * D * T * 2;   // 4 MiB
    f16* ret16   = (f16*)ws;  ws += (size_t)M * D * 2;         // 4 MiB
    f16* x2_16   = (f16*)ws;  ws += (size_t)M * V * 2;         // 32 MiB (residual stream, f16)
    f16* h16     = q16;  // reuse q16+k16 region (8 MiB) after attention

    float* out = (float*)d_out;

    // 1. convert all weights to f16
    conv_all<<<dim3(4096), 256, 0, stream>>>(Wq, Wk, Wv, Wo, Wdown, Wup, Wqkv16);

    // 2. rmsnorm(x) -> xn16
    rmsnorm_kernel<<<dim3(M), 256, 0, stream>>>(x, xn16);

    // 3. QKV GEMM (fused, N=768), K=2048: 64x128 tile -> 768 blocks = 3/CU
    {
        GemmEpi e = {};
        e.out_q = q16; e.out_k = k16; e.out_vT = vT16;
        gemm_nt_64<0><<<dim3(M / 64, 768 / 128), 256, 0, stream>>>(xn16, Wqkv16, V, e);
    }

    // 4. fused decay-attention -> ret16
    attn_kernel<<<dim3(T / 32, Bsz), 256, 0, stream>>>(q16, k16, vT16, ret16, decay_logit);

    // 5. Wo GEMM + residual: x2 (f16) = x + qs*qos*(ret @ Wo^T)  (K=256, 1024 blk)
    {
        GemmEpi e = {};
        e.residf = x; e.outh = x2_16; e.sA = q_scale; e.sB = q_out_scale;
        gemm_nt<1><<<dim3(M / 128, V / 128), 256, 0, stream>>>(ret16, Wo16, D, e);
    }

    // 6. rmsnorm(x2) -> xn16 (reuse)
    rmsnorm_f16<<<dim3(M), 256, 0, stream>>>(x2_16, xn16);

    // 7. Wdown GEMM + bias + exact gelu -> h16, K=2048: 64x128 -> 512 blk = 2/CU
    {
        GemmEpi e = {};
        e.out_h = h16; e.bias = t_bias;
        gemm_nt_64<2><<<dim3(M / 64, R / 128), 256, 0, stream>>>(xn16, Wdown16, V, e);
    }

    // 8. Wup GEMM + residual: out (fp32) = x2 + ts*tos*(h @ Wup^T)  (K=512, 1024 blk)
    {
        GemmEpi e = {};
        e.residh = x2_16; e.outf = out; e.sA = t_scale; e.sB = t_out_scale;
        gemm_nt<3><<<dim3(M / 128, V / 128), 256, 0, stream>>>(h16, Wup16, R, e);
    }
}

// Round 7
// 323.635 us; speedup vs baseline: 1.0190x; 1.0190x over previous
//
#include <hip/hip_runtime.h>
#include <cmath>

typedef _Float16 f16;
typedef _Float16 f16x8 __attribute__((ext_vector_type(8)));
typedef _Float16 f16x4 __attribute__((ext_vector_type(4)));
typedef float f32x4 __attribute__((ext_vector_type(4)));

#define MFMA16(a, b, c) __builtin_amdgcn_mfma_f32_16x16x32_f16(a, b, c, 0, 0, 0)

static constexpr int Bsz = 4;
static constexpr int T = 2048;
static constexpr int V = 2048;
static constexpr int D = 256;
static constexpr int R = 512;
static constexpr int M = Bsz * T;   // 8192

// async global->LDS, 16B per lane; LDS dest = wave-uniform base + lane*16
__device__ __forceinline__ void load_lds16(const f16* g, f16* l) {
    __builtin_amdgcn_global_load_lds(
        (const __attribute__((address_space(1))) unsigned int*)(unsigned long long)g,
        (__attribute__((address_space(3))) unsigned int*)(unsigned int)(unsigned long long)l,
        16, 0, 0);
}

// ---------------------------------------------------------------- convert
__global__ __launch_bounds__(256) void conv_all(const float* __restrict__ s0,
                                                const float* __restrict__ s1,
                                                const float* __restrict__ s2,
                                                const float* __restrict__ s3,
                                                const float* __restrict__ s4,
                                                const float* __restrict__ s5,
                                                f16* __restrict__ dst) {
    int idx = (blockIdx.x * 256 + threadIdx.x) * 4;
    if (idx >= 4194304) return;
    const float* src; int off;
    if      (idx <  524288) { src = s0; off = idx; }
    else if (idx < 1048576) { src = s1; off = idx - 524288; }
    else if (idx < 1572864) { src = s2; off = idx - 1048576; }
    else if (idx < 2097152) { src = s3; off = idx - 1572864; }
    else if (idx < 3145728) { src = s4; off = idx - 2097152; }
    else                    { src = s5; off = idx - 3145728; }
    float4 v = *(const float4*)&src[off];
    f16x4 o;
    o[0] = (f16)v.x; o[1] = (f16)v.y; o[2] = (f16)v.z; o[3] = (f16)v.w;
    *(f16x4*)&dst[idx] = o;
}

// ---------------------------------------------------------------- rmsnorm (fp32 in)
__global__ __launch_bounds__(256) void rmsnorm_kernel(const float* __restrict__ x,
                                                      f16* __restrict__ out) {
    int row = blockIdx.x;
    const float* xr = x + (size_t)row * V;
    int tid = threadIdx.x;
    float4 v0 = ((const float4*)xr)[tid];
    float4 v1 = ((const float4*)xr)[tid + 256];
    float ss = v0.x * v0.x + v0.y * v0.y + v0.z * v0.z + v0.w * v0.w
             + v1.x * v1.x + v1.y * v1.y + v1.z * v1.z + v1.w * v1.w;
    #pragma unroll
    for (int o = 32; o > 0; o >>= 1) ss += __shfl_xor(ss, o);
    __shared__ float wsum[4];
    if ((tid & 63) == 0) wsum[tid >> 6] = ss;
    __syncthreads();
    float tot = wsum[0] + wsum[1] + wsum[2] + wsum[3];
    float s = rsqrtf(tot / (float)V + 1.1920929e-07f);
    f16* orow = out + (size_t)row * V;
    f16x4 o0, o1;
    o0[0] = (f16)(v0.x * s); o0[1] = (f16)(v0.y * s);
    o0[2] = (f16)(v0.z * s); o0[3] = (f16)(v0.w * s);
    o1[0] = (f16)(v1.x * s); o1[1] = (f16)(v1.y * s);
    o1[2] = (f16)(v1.z * s); o1[3] = (f16)(v1.w * s);
    *(f16x4*)&orow[tid * 4] = o0;
    *(f16x4*)&orow[1024 + tid * 4] = o1;
}

// ---------------------------------------------------------------- rmsnorm (f16 in)
__global__ __launch_bounds__(256) void rmsnorm_f16(const f16* __restrict__ x,
                                                   f16* __restrict__ out) {
    int row = blockIdx.x;
    int tid = threadIdx.x;
    const f16* xr = x + (size_t)row * V;
    f16x8 v = *(const f16x8*)&xr[tid * 8];
    float f[8];
    float ss = 0.f;
    #pragma unroll
    for (int j = 0; j < 8; j++) { f[j] = (float)v[j]; ss += f[j] * f[j]; }
    #pragma unroll
    for (int o = 32; o > 0; o >>= 1) ss += __shfl_xor(ss, o);
    __shared__ float wsum[4];
    if ((tid & 63) == 0) wsum[tid >> 6] = ss;
    __syncthreads();
    float tot = wsum[0] + wsum[1] + wsum[2] + wsum[3];
    float s = rsqrtf(tot / (float)V + 1.1920929e-07f);
    f16x8 o;
    #pragma unroll
    for (int j = 0; j < 8; j++) o[j] = (f16)(f[j] * s);
    *(f16x8*)&out[(size_t)row * V + tid * 8] = o;
}

// ---------------------------------------------------------------- GEMM epilogue params
struct GemmEpi {
    const float* residf;
    const f16* residh;
    float* outf;
    f16* outh;
    f16* out_q; f16* out_k; f16* out_vT;
    f16* out_h;
    const float* bias;
    const float* sA; const float* sB;
};

// Epilogue store for one 16-row fragment group (shared by all gemm kernels)
template <int MODE>
__device__ __forceinline__ void epi_store(const GemmEpi& e, float s, f32x4 a,
                                          int gm_base, int gn) {
    #pragma unroll
    for (int i = 0; i < 4; i++) {
        int gm = gm_base + i;
        float vv = a[i];
        if (MODE == 0) {
            if (gn < 256) {
                e.out_q[(size_t)gm * D + gn] = (f16)vv;
            } else if (gn < 512) {
                e.out_k[(size_t)gm * D + (gn - 256)] = (f16)vv;
            } else {
                int d = gn - 512;
                int b = gm >> 11, t = gm & 2047;
                e.out_vT[((size_t)b * D + d) * T + t] = (f16)vv;
            }
        } else if (MODE == 1) {
            size_t o = (size_t)gm * V + gn;
            e.outh[o] = (f16)(e.residf[o] + s * vv);
        } else if (MODE == 2) {
            float z = vv + e.bias[gn];
            float g = 0.5f * z * (1.f + erff(z * 0.70710678118654752f));
            e.out_h[(size_t)gm * R + gn] = (f16)g;
        } else {
            size_t o = (size_t)gm * V + gn;
            e.outf[o] = (float)e.residh[o] + s * vv;
        }
    }
}

// ---------------------------------------------------------------- GEMM NT 128x128 (short-K)
// C[m,n] = sum_k A[m,k]*B[n,k];  A: MxK row-major f16, B: NxK row-major f16
// 256 threads, 4 waves, 128x128 tile, double-buffered global_load_lds staging.
// Used for Wo (K=256) and Wup (K=512): grid 1024 blocks = 4/CU, 32 KiB LDS.
template <int MODE>
__global__ __launch_bounds__(256) void gemm_nt(const f16* __restrict__ A,
                                               const f16* __restrict__ Bm,
                                               int K, GemmEpi e) {
    __shared__ f16 Asl[2][128 * 32];
    __shared__ f16 Bsl[2][128 * 32];
    int tid = threadIdx.x;
    int lane = tid & 63, wv = tid >> 6;
    int wm = wv >> 1, wn = wv & 1;
    int quad = lane >> 4, l16 = lane & 15;
    int m0 = blockIdx.x * 128, n0 = blockIdx.y * 128;
    f32x4 acc[4][4] = {};

    int srow = lane >> 2;
    int scg = (lane & 3) ^ ((lane >> 3) & 3);
    const f16* Ag0 = &A[(size_t)(m0 + 16 * wv + srow) * K + scg * 8];
    const f16* Ag1 = &A[(size_t)(m0 + 16 * (wv + 4) + srow) * K + scg * 8];
    const f16* Bg0 = &Bm[(size_t)(n0 + 16 * wv + srow) * K + scg * 8];
    const f16* Bg1 = &Bm[(size_t)(n0 + 16 * (wv + 4) + srow) * K + scg * 8];
    int lo0 = (16 * wv) * 32, lo1 = (16 * (wv + 4)) * 32;

    int fs = quad ^ ((l16 >> 1) & 3);
    int niter = K >> 5;

    load_lds16(Ag0, &Asl[0][lo0]);
    load_lds16(Ag1, &Asl[0][lo1]);
    load_lds16(Bg0, &Bsl[0][lo0]);
    load_lds16(Bg1, &Bsl[0][lo1]);

    for (int i = 0; i < niter; i++) {
        int cur = i & 1;
        __builtin_amdgcn_s_barrier();
        if (i + 1 < niter) {
            int k0 = (i + 1) << 5;
            int nb = cur ^ 1;
            load_lds16(Ag0 + k0, &Asl[nb][lo0]);
            load_lds16(Ag1 + k0, &Asl[nb][lo1]);
            load_lds16(Bg0 + k0, &Bsl[nb][lo0]);
            load_lds16(Bg1 + k0, &Bsl[nb][lo1]);
            asm volatile("s_waitcnt vmcnt(4)" ::: "memory");
        } else {
            asm volatile("s_waitcnt vmcnt(0)" ::: "memory");
        }
        __builtin_amdgcn_s_barrier();
        f16x8 af[4], bf[4];
        #pragma unroll
        for (int j = 0; j < 4; j++)
            af[j] = *(const f16x8*)&Asl[cur][(64 * wm + 16 * j + l16) * 32 + fs * 8];
        #pragma unroll
        for (int j = 0; j < 4; j++)
            bf[j] = *(const f16x8*)&Bsl[cur][(64 * wn + 16 * j + l16) * 32 + fs * 8];
        #pragma unroll
        for (int mi = 0; mi < 4; mi++)
            #pragma unroll
            for (int ni = 0; ni < 4; ni++)
                acc[mi][ni] = MFMA16(af[mi], bf[ni], acc[mi][ni]);
    }

    float s = 0.f;
    if (MODE == 1 || MODE == 3) s = e.sA[0] * e.sB[0];
    #pragma unroll
    for (int mi = 0; mi < 4; mi++)
        #pragma unroll
        for (int ni = 0; ni < 4; ni++)
            epi_store<MODE>(e, s, acc[mi][ni],
                            m0 + 64 * wm + 16 * mi + quad * 4,
                            n0 + 64 * wn + 16 * ni + l16);
}

// ---------------------------------------------------------------- GEMM NT wave-private (long-K)
// For the K=2048 GEMMs (QKV, Wdown). Same 128x128 tile / 4-wave / BK=32 /
// swizzle / epilogue as gemm_nt, but staging is WAVE-PRIVATE: each wave
// global_load_lds-stages exactly the A-rows (64wm..+63) and B-rows
// (64wn..+63) that IT reads, into its own LDS region. No inter-wave LDS
// sharing -> ZERO s_barrier in the whole kernel. Rationale (rounds 1-6):
// per-iter wall was 1100-1600cyc vs ~310cyc MFMA with MfmaUtil pinned ~21%
// across {deeper stages, split-K, BK=64, 8-phase, smaller tiles} — the
// block-wide barrier couples every wave into the same drain stall each
// iteration. Here each wave self-paces on its own vmcnt (per-wave counter;
// same load->lds->read mechanism as before, minus cross-wave visibility),
// so waves drift and hide each other's latency on the SIMD.
// Cost: A/B tiles staged 2x redundantly per block (wave pairs issue
// identical global addresses -> L1/L2 hits; HBM FETCH unchanged, L3 holds A).
// LDS: 2 stages x 4 waves x (4KB A + 4KB B) = 64 KiB -> 2 blocks/CU.
// Race-free by construction: no LDS word is ever touched by two waves.
template <int MODE>
__global__ __launch_bounds__(256) void gemm_nt_wp(const f16* __restrict__ A,
                                                  const f16* __restrict__ Bm,
                                                  int K, GemmEpi e) {
    __shared__ f16 SL[2][4][2][64 * 32];   // [stage][wave][A|B][64 rows x 32 cols]
    int tid = threadIdx.x;
    int lane = tid & 63, wv = tid >> 6;
    int wm = wv >> 1, wn = wv & 1;
    int quad = lane >> 4, l16 = lane & 15;
    int m0 = blockIdx.x * 128, n0 = blockIdx.y * 128;
    f32x4 acc[4][4] = {};

    // staging addresses: load j covers 16 rows (lane>>2) x 32 cols, colgroup
    // pre-swizzled (scg) so the linear LDS write realizes slot s = scg^((r>>1)&3).
    int srow = lane >> 2;
    int scg = (lane & 3) ^ ((lane >> 3) & 3);
    const f16* Ag[4]; const f16* Bg[4];
    #pragma unroll
    for (int j = 0; j < 4; j++) {
        Ag[j] = &A [(size_t)(m0 + 64 * wm + 16 * j + srow) * K + scg * 8];
        Bg[j] = &Bm[(size_t)(n0 + 64 * wn + 16 * j + srow) * K + scg * 8];
    }

    int fs = quad ^ ((l16 >> 1) & 3);      // read-side swizzled slot
    int niter = K >> 5;

    // prologue: stage tile 0 into stage 0 (8 loads, this wave only)
    #pragma unroll
    for (int j = 0; j < 4; j++) {
        load_lds16(Ag[j], &SL[0][wv][0][16 * j * 32]);
        load_lds16(Bg[j], &SL[0][wv][1][16 * j * 32]);
    }

    for (int i = 0; i < niter; i++) {
        int cur = i & 1;
        if (i + 1 < niter) {
            int k0 = (i + 1) << 5;
            int nb = cur ^ 1;
            #pragma unroll
            for (int j = 0; j < 4; j++) {
                load_lds16(Ag[j] + k0, &SL[nb][wv][0][16 * j * 32]);
                load_lds16(Bg[j] + k0, &SL[nb][wv][1][16 * j * 32]);
            }
            // 16 outstanding: tile i (8, oldest) + tile i+1 (8).
            // Wait for tile i only; tile i+1 stays in flight.
            asm volatile("s_waitcnt vmcnt(8)" ::: "memory");
        } else {
            asm volatile("s_waitcnt vmcnt(0)" ::: "memory");
        }
        f16x8 af[4], bf[4];
        #pragma unroll
        for (int j = 0; j < 4; j++) {
            af[j] = *(const f16x8*)&SL[cur][wv][0][(16 * j + l16) * 32 + fs * 8];
            bf[j] = *(const f16x8*)&SL[cur][wv][1][(16 * j + l16) * 32 + fs * 8];
        }
        #pragma unroll
        for (int mi = 0; mi < 4; mi++)
            #pragma unroll
            for (int ni = 0; ni < 4; ni++)
                acc[mi][ni] = MFMA16(af[mi], bf[ni], acc[mi][ni]);
    }

    float s = 0.f;
    if (MODE == 1 || MODE == 3) s = e.sA[0] * e.sB[0];
    #pragma unroll
    for (int mi = 0; mi < 4; mi++)
        #pragma unroll
        for (int ni = 0; ni < 4; ni++)
            epi_store<MODE>(e, s, acc[mi][ni],
                            m0 + 64 * wm + 16 * mi + quad * 4,
                            n0 + 64 * wn + 16 * ni + l16);
}

// ---------------------------------------------------------------- attention
// retrieved[t,d] = sum_{s>t} decay^(s-t-1) * (q_t . k_s) * v[s,d]
// grid: (T/32, B) = 256 blocks; block 256 (4 waves), QBLK=32.
// Waves split the s-axis (16 cols each) in QK^T and the d-axis (64 cols each)
// in PV. K read straight from L2 (no LDS stage; no cross-wave reuse, L2-fit).
// Decay-window truncation: tiles with max weight < 2^-25 contribute < ~1e-5.
__global__ __launch_bounds__(256) void attn_kernel(const f16* __restrict__ q,
                                                   const f16* __restrict__ k,
                                                   const f16* __restrict__ vT,
                                                   f16* __restrict__ ret,
                                                   const float* __restrict__ decay_logit) {
    __shared__ f16 Psl[32 * 72];
    int tid = threadIdx.x, lane = tid & 63, wv = tid >> 6;
    int quad = lane >> 4, l16 = lane & 15;
    int b = blockIdx.y, t0 = blockIdx.x * 32;
    const f16* qb = q + (size_t)b * T * D;
    const f16* kb = k + (size_t)b * T * D;
    const f16* vb = vT + (size_t)b * D * T;
    f16* rb = ret + (size_t)b * T * D;

    float dl = decay_logit[0];
    float decay = 1.f / (1.f + expf(-dl));
    float l2d = log2f(decay);
    float nl2d = -l2d;

    f16x8 qf[2][8];
    #pragma unroll
    for (int mi = 0; mi < 2; mi++)
        #pragma unroll
        for (int kk = 0; kk < 8; kk++)
            qf[mi][kk] = *(const f16x8*)&qb[(size_t)(t0 + 16 * mi + l16) * D + kk * 32 + quad * 8];

    f32x4 acc2[2][4] = {};

    for (int s0 = t0; s0 < T; s0 += 64) {
        if ((float)(s0 - t0 - 32) * nl2d > 25.f) break;
        int srow = s0 + 16 * wv + l16;
        int srcl = srow < T ? srow : T - 1;
        f32x4 sacc[2] = {};
        #pragma unroll
        for (int kk = 0; kk < 8; kk++) {
            f16x8 bf = *(const f16x8*)&kb[(size_t)srcl * D + kk * 32 + quad * 8];
            sacc[0] = MFMA16(qf[0][kk], bf, sacc[0]);
            sacc[1] = MFMA16(qf[1][kk], bf, sacc[1]);
        }
        __syncthreads();
        #pragma unroll
        for (int mi = 0; mi < 2; mi++) {
            #pragma unroll
            for (int i = 0; i < 4; i++) {
                int t_ = t0 + 16 * mi + quad * 4 + i;
                int diff = srow - t_;
                float w = (diff > 0 && srow < T) ? exp2f((float)(diff - 1) * l2d) : 0.f;
                Psl[(16 * mi + quad * 4 + i) * 72 + 16 * wv + l16] = (f16)(sacc[mi][i] * w);
            }
        }
        __syncthreads();
        #pragma unroll
        for (int kk = 0; kk < 2; kk++) {
            int sb = s0 + kk * 32 + quad * 8;
            if (sb >= T) sb = T - 8;
            f16x8 pa[2], vf[4];
            #pragma unroll
            for (int mi = 0; mi < 2; mi++)
                pa[mi] = *(const f16x8*)&Psl[(16 * mi + l16) * 72 + kk * 32 + quad * 8];
            #pragma unroll
            for (int ni = 0; ni < 4; ni++)
                vf[ni] = *(const f16x8*)&vb[(size_t)(64 * wv + 16 * ni + l16) * T + sb];
            #pragma unroll
            for (int mi = 0; mi < 2; mi++)
                #pragma unroll
                for (int ni = 0; ni < 4; ni++)
                    acc2[mi][ni] = MFMA16(pa[mi], vf[ni], acc2[mi][ni]);
        }
    }

    #pragma unroll
    for (int mi = 0; mi < 2; mi++) {
        #pragma unroll
        for (int ni = 0; ni < 4; ni++) {
            int t_ = t0 + 16 * mi + quad * 4;
            int d_ = 64 * wv + 16 * ni + l16;
            #pragma unroll
            for (int i = 0; i < 4; i++)
                rb[(size_t)(t_ + i) * D + d_] = (f16)acc2[mi][ni][i];
        }
    }
}

// ---------------------------------------------------------------- launch
extern "C" void kernel_launch(void* const* d_in, const int* in_sizes, int n_in,
                              void* d_out, int out_size, void* d_ws, size_t ws_size,
                              hipStream_t stream) {
    const float* x           = (const float*)d_in[0];
    const float* Wq          = (const float*)d_in[1];
    const float* Wk          = (const float*)d_in[2];
    const float* Wv          = (const float*)d_in[3];
    const float* Wo          = (const float*)d_in[4];
    const float* decay_logit = (const float*)d_in[5];
    const float* q_out_scale = (const float*)d_in[6];
    const float* Wdown       = (const float*)d_in[7];
    const float* Wup         = (const float*)d_in[8];
    const float* t_bias      = (const float*)d_in[9];
    const float* t_out_scale = (const float*)d_in[10];
    const float* q_scale     = (const float*)d_in[11];
    const float* t_scale     = (const float*)d_in[12];

    char* ws = (char*)d_ws;
    f16* Wqkv16  = (f16*)ws;  ws += (size_t)768 * V * 2;       // 3 MiB  } contiguous
    f16* Wo16    = (f16*)ws;  ws += (size_t)V * D * 2;         // 1 MiB  } dst for
    f16* Wdown16 = (f16*)ws;  ws += (size_t)R * V * 2;         // 2 MiB  } conv_all
    f16* Wup16   = (f16*)ws;  ws += (size_t)V * R * 2;         // 2 MiB  }
    f16* xn16    = (f16*)ws;  ws += (size_t)M * V * 2;         // 32 MiB (reused as xn2)
    f16* q16     = (f16*)ws;  ws += (size_t)M * D * 2;         // 4 MiB (reused by h16)
    f16* k16     = (f16*)ws;  ws += (size_t)M * D * 2;         // 4 MiB (reused by h16)
    f16* vT16    = (f16*)ws;  ws += (size_t)Bsz * D * T * 2;   // 4 MiB
    f16* ret16   = (f16*)ws;  ws += (size_t)M * D * 2;         // 4 MiB
    f16* x2_16   = (f16*)ws;  ws += (size_t)M * V * 2;         // 32 MiB (residual stream, f16)
    f16* h16     = q16;  // reuse q16+k16 region (8 MiB) after attention

    float* out = (float*)d_out;

    // 1. convert all weights to f16
    conv_all<<<dim3(4096), 256, 0, stream>>>(Wq, Wk, Wv, Wo, Wdown, Wup, Wqkv16);

    // 2. rmsnorm(x) -> xn16
    rmsnorm_kernel<<<dim3(M), 256, 0, stream>>>(x, xn16);

    // 3. QKV GEMM (fused, N=768), K=2048: wave-private barrier-free kernel
    {
        GemmEpi e = {};
        e.out_q = q16; e.out_k = k16; e.out_vT = vT16;
        gemm_nt_wp<0><<<dim3(M / 128, 768 / 128), 256, 0, stream>>>(xn16, Wqkv16, V, e);
    }

    // 4. fused decay-attention -> ret16
    attn_kernel<<<dim3(T / 32, Bsz), 256, 0, stream>>>(q16, k16, vT16, ret16, decay_logit);

    // 5. Wo GEMM + residual: x2 (f16) = x + qs*qos*(ret @ Wo^T)  (K=256, 1024 blk)
    {
        GemmEpi e = {};
        e.residf = x; e.outh = x2_16; e.sA = q_scale; e.sB = q_out_scale;
        gemm_nt<1><<<dim3(M / 128, V / 128), 256, 0, stream>>>(ret16, Wo16, D, e);
    }

    // 6. rmsnorm(x2) -> xn16 (reuse)
    rmsnorm_f16<<<dim3(M), 256, 0, stream>>>(x2_16, xn16);

    // 7. Wdown GEMM + bias + exact gelu -> h16, K=2048: wave-private kernel
    {
        GemmEpi e = {};
        e.out_h = h16; e.bias = t_bias;
        gemm_nt_wp<2><<<dim3(M / 128, R / 128), 256, 0, stream>>>(xn16, Wdown16, V, e);
    }

    // 8. Wup GEMM + residual: out (fp32) = x2 + ts*tos*(h @ Wup^T)  (K=512, 1024 blk)
    {
        GemmEpi e = {};
        e.residh = x2_16; e.outf = out; e.sA = t_scale; e.sB = t_out_scale;
        gemm_nt<3><<<dim3(M / 128, V / 128), 256, 0, stream>>>(h16, Wup16, R, e);
    }
}

// Round 8
// 306.147 us; speedup vs baseline: 1.0772x; 1.0571x over previous
//
#include <hip/hip_runtime.h>
#include <cmath>

typedef _Float16 f16;
typedef _Float16 f16x8 __attribute__((ext_vector_type(8)));
typedef _Float16 f16x4 __attribute__((ext_vector_type(4)));
typedef float f32x4 __attribute__((ext_vector_type(4)));

#define MFMA16(a, b, c) __builtin_amdgcn_mfma_f32_16x16x32_f16(a, b, c, 0, 0, 0)

static constexpr int Bsz = 4;
static constexpr int T = 2048;
static constexpr int V = 2048;
static constexpr int D = 256;
static constexpr int R = 512;
static constexpr int M = Bsz * T;   // 8192

// async global->LDS, 16B per lane; LDS dest = wave-uniform base + lane*16
__device__ __forceinline__ void load_lds16(const f16* g, f16* l) {
    __builtin_amdgcn_global_load_lds(
        (const __attribute__((address_space(1))) unsigned int*)(unsigned long long)g,
        (__attribute__((address_space(3))) unsigned int*)(unsigned int)(unsigned long long)l,
        16, 0, 0);
}

// ---------------------------------------------------------------- convert
__global__ __launch_bounds__(256) void conv_all(const float* __restrict__ s0,
                                                const float* __restrict__ s1,
                                                const float* __restrict__ s2,
                                                const float* __restrict__ s3,
                                                const float* __restrict__ s4,
                                                const float* __restrict__ s5,
                                                f16* __restrict__ dst) {
    int idx = (blockIdx.x * 256 + threadIdx.x) * 4;
    if (idx >= 4194304) return;
    const float* src; int off;
    if      (idx <  524288) { src = s0; off = idx; }
    else if (idx < 1048576) { src = s1; off = idx - 524288; }
    else if (idx < 1572864) { src = s2; off = idx - 1048576; }
    else if (idx < 2097152) { src = s3; off = idx - 1572864; }
    else if (idx < 3145728) { src = s4; off = idx - 2097152; }
    else                    { src = s5; off = idx - 3145728; }
    float4 v = *(const float4*)&src[off];
    f16x4 o;
    o[0] = (f16)v.x; o[1] = (f16)v.y; o[2] = (f16)v.z; o[3] = (f16)v.w;
    *(f16x4*)&dst[idx] = o;
}

// ---------------------------------------------------------------- rmsnorm (fp32 in)
__global__ __launch_bounds__(256) void rmsnorm_kernel(const float* __restrict__ x,
                                                      f16* __restrict__ out) {
    int row = blockIdx.x;
    const float* xr = x + (size_t)row * V;
    int tid = threadIdx.x;
    float4 v0 = ((const float4*)xr)[tid];
    float4 v1 = ((const float4*)xr)[tid + 256];
    float ss = v0.x * v0.x + v0.y * v0.y + v0.z * v0.z + v0.w * v0.w
             + v1.x * v1.x + v1.y * v1.y + v1.z * v1.z + v1.w * v1.w;
    #pragma unroll
    for (int o = 32; o > 0; o >>= 1) ss += __shfl_xor(ss, o);
    __shared__ float wsum[4];
    if ((tid & 63) == 0) wsum[tid >> 6] = ss;
    __syncthreads();
    float tot = wsum[0] + wsum[1] + wsum[2] + wsum[3];
    float s = rsqrtf(tot / (float)V + 1.1920929e-07f);
    f16* orow = out + (size_t)row * V;
    f16x4 o0, o1;
    o0[0] = (f16)(v0.x * s); o0[1] = (f16)(v0.y * s);
    o0[2] = (f16)(v0.z * s); o0[3] = (f16)(v0.w * s);
    o1[0] = (f16)(v1.x * s); o1[1] = (f16)(v1.y * s);
    o1[2] = (f16)(v1.z * s); o1[3] = (f16)(v1.w * s);
    *(f16x4*)&orow[tid * 4] = o0;
    *(f16x4*)&orow[1024 + tid * 4] = o1;
}

// ---------------------------------------------------------------- GEMM epilogue params
struct GemmEpi {
    const float* residf;
    const f16* residh;
    float* outf;
    f16* outh;
    f16* out_q; f16* out_k; f16* out_vT;
    f16* out_h;
    const float* bias;
    const float* sA; const float* sB;
    float* rowss;          // MODE 1: accumulate per-row sum(x2^2); MODE 2: read
};

// Epilogue store for one 16-row fragment group.
// MODE 2 applies the factored-out rmsnorm scale s[gm] = rsqrt(rowss/V + eps)
// BEFORE bias+gelu (rms(x2) @ W^T == s[m] * (x2 @ W^T): per-row scale factors
// out of the dot product, so the rmsnorm pass over x2 is never materialized).
template <int MODE>
__device__ __forceinline__ void epi_store(const GemmEpi& e, float s, f32x4 a,
                                          int gm_base, int gn) {
    #pragma unroll
    for (int i = 0; i < 4; i++) {
        int gm = gm_base + i;
        float vv = a[i];
        if (MODE == 0) {
            if (gn < 256) {
                e.out_q[(size_t)gm * D + gn] = (f16)vv;
            } else if (gn < 512) {
                e.out_k[(size_t)gm * D + (gn - 256)] = (f16)vv;
            } else {
                int d = gn - 512;
                int b = gm >> 11, t = gm & 2047;
                e.out_vT[((size_t)b * D + d) * T + t] = (f16)vv;
            }
        } else if (MODE == 1) {
            size_t o = (size_t)gm * V + gn;
            e.outh[o] = (f16)(e.residf[o] + s * vv);
        } else if (MODE == 2) {
            float sc = rsqrtf(e.rowss[gm] * (1.f / 2048.f) + 1.1920929e-07f);
            float z = sc * vv + e.bias[gn];
            float g = 0.5f * z * (1.f + erff(z * 0.70710678118654752f));
            e.out_h[(size_t)gm * R + gn] = (f16)g;
        } else {
            size_t o = (size_t)gm * V + gn;
            e.outf[o] = (float)e.residh[o] + s * vv;
        }
    }
}

// ---------------------------------------------------------------- GEMM NT 128x128 (short-K)
// C[m,n] = sum_k A[m,k]*B[n,k];  A: MxK row-major f16, B: NxK row-major f16
// 256 threads, 4 waves, 128x128 tile, double-buffered global_load_lds staging.
// Used for Wo (K=256, MODE 1) and Wup (K=512, MODE 3): 1024 blocks = 4/CU.
// MODE 1 additionally reduces per-row sum(x2^2) (LDS tree + 1 atomic/row) so
// the downstream rmsnorm pass is eliminated (scale factored into Wdown epi).
template <int MODE>
__global__ __launch_bounds__(256) void gemm_nt(const f16* __restrict__ A,
                                               const f16* __restrict__ Bm,
                                               int K, GemmEpi e) {
    __shared__ f16 Asl[2][128 * 32];
    __shared__ f16 Bsl[2][128 * 32];
    int tid = threadIdx.x;
    int lane = tid & 63, wv = tid >> 6;
    int wm = wv >> 1, wn = wv & 1;
    int quad = lane >> 4, l16 = lane & 15;
    int m0 = blockIdx.x * 128, n0 = blockIdx.y * 128;
    f32x4 acc[4][4] = {};

    int srow = lane >> 2;
    int scg = (lane & 3) ^ ((lane >> 3) & 3);
    const f16* Ag0 = &A[(size_t)(m0 + 16 * wv + srow) * K + scg * 8];
    const f16* Ag1 = &A[(size_t)(m0 + 16 * (wv + 4) + srow) * K + scg * 8];
    const f16* Bg0 = &Bm[(size_t)(n0 + 16 * wv + srow) * K + scg * 8];
    const f16* Bg1 = &Bm[(size_t)(n0 + 16 * (wv + 4) + srow) * K + scg * 8];
    int lo0 = (16 * wv) * 32, lo1 = (16 * (wv + 4)) * 32;

    int fs = quad ^ ((l16 >> 1) & 3);
    int niter = K >> 5;

    load_lds16(Ag0, &Asl[0][lo0]);
    load_lds16(Ag1, &Asl[0][lo1]);
    load_lds16(Bg0, &Bsl[0][lo0]);
    load_lds16(Bg1, &Bsl[0][lo1]);

    for (int i = 0; i < niter; i++) {
        int cur = i & 1;
        __builtin_amdgcn_s_barrier();
        if (i + 1 < niter) {
            int k0 = (i + 1) << 5;
            int nb = cur ^ 1;
            load_lds16(Ag0 + k0, &Asl[nb][lo0]);
            load_lds16(Ag1 + k0, &Asl[nb][lo1]);
            load_lds16(Bg0 + k0, &Bsl[nb][lo0]);
            load_lds16(Bg1 + k0, &Bsl[nb][lo1]);
            asm volatile("s_waitcnt vmcnt(4)" ::: "memory");
        } else {
            asm volatile("s_waitcnt vmcnt(0)" ::: "memory");
        }
        __builtin_amdgcn_s_barrier();
        f16x8 af[4], bf[4];
        #pragma unroll
        for (int j = 0; j < 4; j++)
            af[j] = *(const f16x8*)&Asl[cur][(64 * wm + 16 * j + l16) * 32 + fs * 8];
        #pragma unroll
        for (int j = 0; j < 4; j++)
            bf[j] = *(const f16x8*)&Bsl[cur][(64 * wn + 16 * j + l16) * 32 + fs * 8];
        #pragma unroll
        for (int mi = 0; mi < 4; mi++)
            #pragma unroll
            for (int ni = 0; ni < 4; ni++)
                acc[mi][ni] = MFMA16(af[mi], bf[ni], acc[mi][ni]);
    }

    float s = 0.f;
    if (MODE == 1 || MODE == 3) s = e.sA[0] * e.sB[0];

    if constexpr (MODE == 1) {
        // fused epilogue: write x2 = x + s*vv AND accumulate per-row sum(x2^2).
        // rbuf[row_local][wn*16+l16]: 32 partials per row (each = sum over 4 ni).
        float* rbuf = (float*)&Asl[0][0];   // 16 KiB = 128*32 floats (reuse staging LDS)
        __syncthreads();                    // all K-loop LDS reads retired
        #pragma unroll
        for (int mi = 0; mi < 4; mi++) {
            #pragma unroll
            for (int i = 0; i < 4; i++) {
                int rl = 64 * wm + 16 * mi + quad * 4 + i;
                int gm = m0 + rl;
                float p = 0.f;
                #pragma unroll
                for (int ni = 0; ni < 4; ni++) {
                    int gn = n0 + 64 * wn + 16 * ni + l16;
                    size_t o = (size_t)gm * V + gn;
                    float val = e.residf[o] + s * acc[mi][ni][i];
                    e.outh[o] = (f16)val;
                    p += val * val;
                }
                rbuf[rl * 32 + wn * 16 + l16] = p;
            }
        }
        __syncthreads();
        if (tid < 128) {
            float tot = 0.f;
            #pragma unroll
            for (int j = 0; j < 32; j++) tot += rbuf[tid * 32 + j];
            atomicAdd(&e.rowss[m0 + tid], tot);
        }
    } else {
        #pragma unroll
        for (int mi = 0; mi < 4; mi++)
            #pragma unroll
            for (int ni = 0; ni < 4; ni++)
                epi_store<MODE>(e, s, acc[mi][ni],
                                m0 + 64 * wm + 16 * mi + quad * 4,
                                n0 + 64 * wn + 16 * ni + l16);
    }
}

// ---------------------------------------------------------------- GEMM NT (BK=64, long-K)
// For the K=2048 GEMMs (QKV MODE 0, Wdown MODE 2) — fastest measured variant
// (round 4: QKV 43.4us). Two K=32 sub-tiles per barrier-pair; 64 KiB LDS.
// Swizzle: LDS[r][s] holds global colgroup s^(r&7); source lane address
// pre-swizzled (gcol=(lane&7)^(lane>>3)) so global_load_lds writes linearly.
template <int MODE>
__global__ __launch_bounds__(256) void gemm_nt_k64(const f16* __restrict__ A,
                                                   const f16* __restrict__ Bm,
                                                   int K, GemmEpi e) {
    __shared__ f16 Asl[2][128 * 64];
    __shared__ f16 Bsl[2][128 * 64];
    int tid = threadIdx.x;
    int lane = tid & 63, wv = tid >> 6;
    int wm = wv >> 1, wn = wv & 1;
    int quad = lane >> 4, l16 = lane & 15;
    int m0 = blockIdx.x * 128, n0 = blockIdx.y * 128;
    f32x4 acc[4][4] = {};

    int r8 = lane >> 3;
    int gcol = (lane & 7) ^ r8;
    const f16* Ag[4]; const f16* Bg[4]; int lo[4];
    #pragma unroll
    for (int j = 0; j < 4; j++) {
        int rbase = 8 * (wv + 4 * j);
        Ag[j] = &A[(size_t)(m0 + rbase + r8) * K + gcol * 8];
        Bg[j] = &Bm[(size_t)(n0 + rbase + r8) * K + gcol * 8];
        lo[j] = rbase * 64;
    }
    int niter = K >> 6;

    #pragma unroll
    for (int j = 0; j < 4; j++) {
        load_lds16(Ag[j], &Asl[0][lo[j]]);
        load_lds16(Bg[j], &Bsl[0][lo[j]]);
    }

    for (int i = 0; i < niter; i++) {
        int cur = i & 1;
        __builtin_amdgcn_s_barrier();
        if (i + 1 < niter) {
            int k0 = (i + 1) << 6;
            int nb = cur ^ 1;
            #pragma unroll
            for (int j = 0; j < 4; j++) {
                load_lds16(Ag[j] + k0, &Asl[nb][lo[j]]);
                load_lds16(Bg[j] + k0, &Bsl[nb][lo[j]]);
            }
            asm volatile("s_waitcnt vmcnt(8)" ::: "memory");
        } else {
            asm volatile("s_waitcnt vmcnt(0)" ::: "memory");
        }
        __builtin_amdgcn_s_barrier();
        #pragma unroll
        for (int kk = 0; kk < 2; kk++) {
            f16x8 af[4], bf[4];
            #pragma unroll
            for (int j = 0; j < 4; j++) {
                int row = 64 * wm + 16 * j + l16;
                int sl = (kk * 4 + quad) ^ (l16 & 7);
                af[j] = *(const f16x8*)&Asl[cur][row * 64 + sl * 8];
            }
            #pragma unroll
            for (int j = 0; j < 4; j++) {
                int row = 64 * wn + 16 * j + l16;
                int sl = (kk * 4 + quad) ^ (l16 & 7);
                bf[j] = *(const f16x8*)&Bsl[cur][row * 64 + sl * 8];
            }
            #pragma unroll
            for (int mi = 0; mi < 4; mi++)
                #pragma unroll
                for (int ni = 0; ni < 4; ni++)
                    acc[mi][ni] = MFMA16(af[mi], bf[ni], acc[mi][ni]);
        }
    }

    float s = 0.f;
    if (MODE == 1 || MODE == 3) s = e.sA[0] * e.sB[0];
    #pragma unroll
    for (int mi = 0; mi < 4; mi++)
        #pragma unroll
        for (int ni = 0; ni < 4; ni++)
            epi_store<MODE>(e, s, acc[mi][ni],
                            m0 + 64 * wm + 16 * mi + quad * 4,
                            n0 + 64 * wn + 16 * ni + l16);
}

// ---------------------------------------------------------------- attention
// retrieved[t,d] = sum_{s>t} decay^(s-t-1) * (q_t . k_s) * v[s,d]
// grid: (T/32, B) = 256 blocks; block 256 (4 waves), QBLK=32.
// Waves split the s-axis (16 cols each) in QK^T and the d-axis (64 cols each)
// in PV. K read straight from L2 (no LDS stage; no cross-wave reuse, L2-fit).
// Decay-window truncation: tiles with max weight < 2^-25 contribute < ~1e-5.
__global__ __launch_bounds__(256) void attn_kernel(const f16* __restrict__ q,
                                                   const f16* __restrict__ k,
                                                   const f16* __restrict__ vT,
                                                   f16* __restrict__ ret,
                                                   const float* __restrict__ decay_logit) {
    __shared__ f16 Psl[32 * 72];
    int tid = threadIdx.x, lane = tid & 63, wv = tid >> 6;
    int quad = lane >> 4, l16 = lane & 15;
    int b = blockIdx.y, t0 = blockIdx.x * 32;
    const f16* qb = q + (size_t)b * T * D;
    const f16* kb = k + (size_t)b * T * D;
    const f16* vb = vT + (size_t)b * D * T;
    f16* rb = ret + (size_t)b * T * D;

    float dl = decay_logit[0];
    float decay = 1.f / (1.f + expf(-dl));
    float l2d = log2f(decay);
    float nl2d = -l2d;

    f16x8 qf[2][8];
    #pragma unroll
    for (int mi = 0; mi < 2; mi++)
        #pragma unroll
        for (int kk = 0; kk < 8; kk++)
            qf[mi][kk] = *(const f16x8*)&qb[(size_t)(t0 + 16 * mi + l16) * D + kk * 32 + quad * 8];

    f32x4 acc2[2][4] = {};

    for (int s0 = t0; s0 < T; s0 += 64) {
        if ((float)(s0 - t0 - 32) * nl2d > 25.f) break;
        int srow = s0 + 16 * wv + l16;
        int srcl = srow < T ? srow : T - 1;
        f32x4 sacc[2] = {};
        #pragma unroll
        for (int kk = 0; kk < 8; kk++) {
            f16x8 bf = *(const f16x8*)&kb[(size_t)srcl * D + kk * 32 + quad * 8];
            sacc[0] = MFMA16(qf[0][kk], bf, sacc[0]);
            sacc[1] = MFMA16(qf[1][kk], bf, sacc[1]);
        }
        __syncthreads();
        #pragma unroll
        for (int mi = 0; mi < 2; mi++) {
            #pragma unroll
            for (int i = 0; i < 4; i++) {
                int t_ = t0 + 16 * mi + quad * 4 + i;
                int diff = srow - t_;
                float w = (diff > 0 && srow < T) ? exp2f((float)(diff - 1) * l2d) : 0.f;
                Psl[(16 * mi + quad * 4 + i) * 72 + 16 * wv + l16] = (f16)(sacc[mi][i] * w);
            }
        }
        __syncthreads();
        #pragma unroll
        for (int kk = 0; kk < 2; kk++) {
            int sb = s0 + kk * 32 + quad * 8;
            if (sb >= T) sb = T - 8;
            f16x8 pa[2], vf[4];
            #pragma unroll
            for (int mi = 0; mi < 2; mi++)
                pa[mi] = *(const f16x8*)&Psl[(16 * mi + l16) * 72 + kk * 32 + quad * 8];
            #pragma unroll
            for (int ni = 0; ni < 4; ni++)
                vf[ni] = *(const f16x8*)&vb[(size_t)(64 * wv + 16 * ni + l16) * T + sb];
            #pragma unroll
            for (int mi = 0; mi < 2; mi++)
                #pragma unroll
                for (int ni = 0; ni < 4; ni++)
                    acc2[mi][ni] = MFMA16(pa[mi], vf[ni], acc2[mi][ni]);
        }
    }

    #pragma unroll
    for (int mi = 0; mi < 2; mi++) {
        #pragma unroll
        for (int ni = 0; ni < 4; ni++) {
            int t_ = t0 + 16 * mi + quad * 4;
            int d_ = 64 * wv + 16 * ni + l16;
            #pragma unroll
            for (int i = 0; i < 4; i++)
                rb[(size_t)(t_ + i) * D + d_] = (f16)acc2[mi][ni][i];
        }
    }
}

// ---------------------------------------------------------------- launch
extern "C" void kernel_launch(void* const* d_in, const int* in_sizes, int n_in,
                              void* d_out, int out_size, void* d_ws, size_t ws_size,
                              hipStream_t stream) {
    const float* x           = (const float*)d_in[0];
    const float* Wq          = (const float*)d_in[1];
    const float* Wk          = (const float*)d_in[2];
    const float* Wv          = (const float*)d_in[3];
    const float* Wo          = (const float*)d_in[4];
    const float* decay_logit = (const float*)d_in[5];
    const float* q_out_scale = (const float*)d_in[6];
    const float* Wdown       = (const float*)d_in[7];
    const float* Wup         = (const float*)d_in[8];
    const float* t_bias      = (const float*)d_in[9];
    const float* t_out_scale = (const float*)d_in[10];
    const float* q_scale     = (const float*)d_in[11];
    const float* t_scale     = (const float*)d_in[12];

    char* ws = (char*)d_ws;
    f16* Wqkv16  = (f16*)ws;  ws += (size_t)768 * V * 2;       // 3 MiB  } contiguous
    f16* Wo16    = (f16*)ws;  ws += (size_t)V * D * 2;         // 1 MiB  } dst for
    f16* Wdown16 = (f16*)ws;  ws += (size_t)R * V * 2;         // 2 MiB  } conv_all
    f16* Wup16   = (f16*)ws;  ws += (size_t)V * R * 2;         // 2 MiB  }
    f16* xn16    = (f16*)ws;  ws += (size_t)M * V * 2;         // 32 MiB (pass-1 rmsnorm out)
    f16* q16     = (f16*)ws;  ws += (size_t)M * D * 2;         // 4 MiB (reused by h16)
    f16* k16     = (f16*)ws;  ws += (size_t)M * D * 2;         // 4 MiB (reused by h16)
    f16* vT16    = (f16*)ws;  ws += (size_t)Bsz * D * T * 2;   // 4 MiB
    f16* ret16   = (f16*)ws;  ws += (size_t)M * D * 2;         // 4 MiB
    f16* x2_16   = (f16*)ws;  ws += (size_t)M * V * 2;         // 32 MiB (residual stream, f16)
    float* rowss = (float*)ws; ws += (size_t)M * 4;            // 32 KiB (sum x2^2 per row)
    f16* h16     = q16;  // reuse q16+k16 region (8 MiB) after attention

    float* out = (float*)d_out;

    // 1. convert all weights to f16; zero the row-sum-of-squares accumulator
    conv_all<<<dim3(4096), 256, 0, stream>>>(Wq, Wk, Wv, Wo, Wdown, Wup, Wqkv16);
    hipMemsetAsync(rowss, 0, (size_t)M * 4, stream);

    // 2. rmsnorm(x) -> xn16
    rmsnorm_kernel<<<dim3(M), 256, 0, stream>>>(x, xn16);

    // 3. QKV GEMM (fused, N=768), K=2048 -> BK=64 kernel (fastest measured)
    {
        GemmEpi e = {};
        e.out_q = q16; e.out_k = k16; e.out_vT = vT16;
        gemm_nt_k64<0><<<dim3(M / 128, 768 / 128), 256, 0, stream>>>(xn16, Wqkv16, V, e);
    }

    // 4. fused decay-attention -> ret16
    attn_kernel<<<dim3(T / 32, Bsz), 256, 0, stream>>>(q16, k16, vT16, ret16, decay_logit);

    // 5. Wo GEMM + residual + row-ss: x2 = x + qs*qos*(ret @ Wo^T), rowss += x2^2
    {
        GemmEpi e = {};
        e.residf = x; e.outh = x2_16; e.sA = q_scale; e.sB = q_out_scale;
        e.rowss = rowss;
        gemm_nt<1><<<dim3(M / 128, V / 128), 256, 0, stream>>>(ret16, Wo16, D, e);
    }

    // 6. (rmsnorm pass 2 eliminated: scale factored into Wdown epilogue)

    // 7. Wdown GEMM on RAW x2 + per-row rms scale + bias + exact gelu -> h16
    {
        GemmEpi e = {};
        e.out_h = h16; e.bias = t_bias; e.rowss = rowss;
        gemm_nt_k64<2><<<dim3(M / 128, R / 128), 256, 0, stream>>>(x2_16, Wdown16, V, e);
    }

    // 8. Wup GEMM + residual: out (fp32) = x2 + ts*tos*(h @ Wup^T)  (K=512)
    {
        GemmEpi e = {};
        e.residh = x2_16; e.outf = out; e.sA = t_scale; e.sB = t_out_scale;
        gemm_nt<3><<<dim3(M / 128, V / 128), 256, 0, stream>>>(h16, Wup16, R, e);
    }
}

// Round 10
// 303.645 us; speedup vs baseline: 1.0860x; 1.0082x over previous
//
#include <hip/hip_runtime.h>
#include <cmath>

typedef _Float16 f16;
typedef _Float16 f16x8 __attribute__((ext_vector_type(8)));
typedef _Float16 f16x4 __attribute__((ext_vector_type(4)));
typedef float f32x4 __attribute__((ext_vector_type(4)));

#define MFMA16(a, b, c) __builtin_amdgcn_mfma_f32_16x16x32_f16(a, b, c, 0, 0, 0)

static constexpr int Bsz = 4;
static constexpr int T = 2048;
static constexpr int V = 2048;
static constexpr int D = 256;
static constexpr int R = 512;
static constexpr int M = Bsz * T;   // 8192

// async global->LDS, 16B per lane; LDS dest = wave-uniform base + lane*16
__device__ __forceinline__ void load_lds16(const f16* g, f16* l) {
    __builtin_amdgcn_global_load_lds(
        (const __attribute__((address_space(1))) unsigned int*)(unsigned long long)g,
        (__attribute__((address_space(3))) unsigned int*)(unsigned int)(unsigned long long)l,
        16, 0, 0);
}

// ---------------------------------------------------------------- prep
// One launch: blocks [0,4096) convert the 6 weight matrices to f16;
// blocks [4096,12288) rmsnorm x -> xn16 (f16) and zero rowss[row].
// (Folds the old conv_all + rmsnorm_kernel + hipMemsetAsync into one dispatch.)
__global__ __launch_bounds__(256) void prep_kernel(const float* __restrict__ s0,
                                                   const float* __restrict__ s1,
                                                   const float* __restrict__ s2,
                                                   const float* __restrict__ s3,
                                                   const float* __restrict__ s4,
                                                   const float* __restrict__ s5,
                                                   f16* __restrict__ dst,
                                                   const float* __restrict__ x,
                                                   f16* __restrict__ xn,
                                                   float* __restrict__ rowss) {
    int bid = blockIdx.x;
    int tid = threadIdx.x;
    if (bid < 4096) {
        int idx = (bid * 256 + tid) * 4;
        const float* src; int off;
        if      (idx <  524288) { src = s0; off = idx; }
        else if (idx < 1048576) { src = s1; off = idx - 524288; }
        else if (idx < 1572864) { src = s2; off = idx - 1048576; }
        else if (idx < 2097152) { src = s3; off = idx - 1572864; }
        else if (idx < 3145728) { src = s4; off = idx - 2097152; }
        else                    { src = s5; off = idx - 3145728; }
        float4 v = *(const float4*)&src[off];
        f16x4 o;
        o[0] = (f16)v.x; o[1] = (f16)v.y; o[2] = (f16)v.z; o[3] = (f16)v.w;
        *(f16x4*)&dst[idx] = o;
        return;
    }
    int row = bid - 4096;
    const float* xr = x + (size_t)row * V;
    float4 v0 = ((const float4*)xr)[tid];
    float4 v1 = ((const float4*)xr)[tid + 256];
    float ss = v0.x * v0.x + v0.y * v0.y + v0.z * v0.z + v0.w * v0.w
             + v1.x * v1.x + v1.y * v1.y + v1.z * v1.z + v1.w * v1.w;
    #pragma unroll
    for (int o = 32; o > 0; o >>= 1) ss += __shfl_xor(ss, o);
    __shared__ float wsum[4];
    if ((tid & 63) == 0) wsum[tid >> 6] = ss;
    __syncthreads();
    float tot = wsum[0] + wsum[1] + wsum[2] + wsum[3];
    float s = rsqrtf(tot / (float)V + 1.1920929e-07f);
    f16* orow = xn + (size_t)row * V;
    f16x4 o0, o1;
    o0[0] = (f16)(v0.x * s); o0[1] = (f16)(v0.y * s);
    o0[2] = (f16)(v0.z * s); o0[3] = (f16)(v0.w * s);
    o1[0] = (f16)(v1.x * s); o1[1] = (f16)(v1.y * s);
    o1[2] = (f16)(v1.z * s); o1[3] = (f16)(v1.w * s);
    *(f16x4*)&orow[tid * 4] = o0;
    *(f16x4*)&orow[1024 + tid * 4] = o1;
    if (tid == 0) rowss[row] = 0.f;     // zero accumulator for Wo's row-ss
}

// ---------------------------------------------------------------- GEMM epilogue params
struct GemmEpi {
    const float* residf;
    const f16* residh;
    float* outf;
    f16* outh;
    f16* out_q; f16* out_k; f16* out_vT;
    f16* out_h;
    const float* bias;
    const float* sA; const float* sB;
    float* rowss;          // MODE 1: accumulate per-row sum(x2^2); MODE 2: read
};

// Epilogue store for one 16-row fragment group.
// MODE 2 applies the factored-out rmsnorm scale s[gm] = rsqrt(rowss/V + eps)
// BEFORE bias+gelu (rms(x2) @ W^T == s[m] * (x2 @ W^T)).
template <int MODE>
__device__ __forceinline__ void epi_store(const GemmEpi& e, float s, f32x4 a,
                                          int gm_base, int gn) {
    #pragma unroll
    for (int i = 0; i < 4; i++) {
        int gm = gm_base + i;
        float vv = a[i];
        if (MODE == 0) {
            if (gn < 256) {
                e.out_q[(size_t)gm * D + gn] = (f16)vv;
            } else if (gn < 512) {
                e.out_k[(size_t)gm * D + (gn - 256)] = (f16)vv;
            } else {
                int d = gn - 512;
                int b = gm >> 11, t = gm & 2047;
                e.out_vT[((size_t)b * D + d) * T + t] = (f16)vv;
            }
        } else if (MODE == 1) {
            size_t o = (size_t)gm * V + gn;
            e.outh[o] = (f16)(e.residf[o] + s * vv);
        } else if (MODE == 2) {
            float sc = rsqrtf(e.rowss[gm] * (1.f / 2048.f) + 1.1920929e-07f);
            float z = sc * vv + e.bias[gn];
            float g = 0.5f * z * (1.f + erff(z * 0.70710678118654752f));
            e.out_h[(size_t)gm * R + gn] = (f16)g;
        } else {
            size_t o = (size_t)gm * V + gn;
            e.outf[o] = (float)e.residh[o] + s * vv;
        }
    }
}

// ---------------------------------------------------------------- GEMM NT 128x192 (QKV)
// Rounds 0-8 model: these GEMMs are STAGING-BW-limited — perf = staging_rate
// x intensity. 128x128 = 64 FLOP/B -> 594 TF measured (r8). Widening to
// BN=192 raises intensity to 76.8 FLOP/B AND makes the grid exactly
// (8192/128)x(768/192) = 256 blocks = one full round (was 1.5 rounds).
// 4 waves (2Mx2N), per-wave 64x96 output: acc[4][6] (96 VGPR, all static).
// LDS 40 KiB (A 2x8KB + B 2x12KB) -> 2-4 blocks/CU for staging concurrency.
// 5 staging loads/iter/wave (2 A + 3 B) -> steady vmcnt(5). Same verified
// XOR swizzle as r0: LDS[r][s] = colgroup s^((r>>1)&3), pre-swizzled source.
template <int MODE>
__global__ __launch_bounds__(256) void gemm_nt_192(const f16* __restrict__ A,
                                                   const f16* __restrict__ Bm,
                                                   int K, GemmEpi e) {
    __shared__ f16 Asl[2][128 * 32];
    __shared__ f16 Bsl[2][192 * 32];
    int tid = threadIdx.x;
    int lane = tid & 63, wv = tid >> 6;
    int wm = wv >> 1, wn = wv & 1;
    int quad = lane >> 4, l16 = lane & 15;
    int m0 = blockIdx.x * 128, n0 = blockIdx.y * 192;
    f32x4 acc[4][6] = {};

    int srow = lane >> 2;
    int scg = (lane & 3) ^ ((lane >> 3) & 3);
    const f16* Ag0 = &A[(size_t)(m0 + 16 * wv + srow) * K + scg * 8];
    const f16* Ag1 = &A[(size_t)(m0 + 16 * (wv + 4) + srow) * K + scg * 8];
    const f16* Bg0 = &Bm[(size_t)(n0 + 16 * wv + srow) * K + scg * 8];
    const f16* Bg1 = &Bm[(size_t)(n0 + 16 * (wv + 4) + srow) * K + scg * 8];
    const f16* Bg2 = &Bm[(size_t)(n0 + 16 * (wv + 8) + srow) * K + scg * 8];
    int lo0 = (16 * wv) * 32, lo1 = (16 * (wv + 4)) * 32, lo2 = (16 * (wv + 8)) * 32;

    int fs = quad ^ ((l16 >> 1) & 3);
    int niter = K >> 5;

    load_lds16(Ag0, &Asl[0][lo0]);
    load_lds16(Ag1, &Asl[0][lo1]);
    load_lds16(Bg0, &Bsl[0][lo0]);
    load_lds16(Bg1, &Bsl[0][lo1]);
    load_lds16(Bg2, &Bsl[0][lo2]);

    for (int i = 0; i < niter; i++) {
        int cur = i & 1;
        __builtin_amdgcn_s_barrier();
        if (i + 1 < niter) {
            int k0 = (i + 1) << 5;
            int nb = cur ^ 1;
            load_lds16(Ag0 + k0, &Asl[nb][lo0]);
            load_lds16(Ag1 + k0, &Asl[nb][lo1]);
            load_lds16(Bg0 + k0, &Bsl[nb][lo0]);
            load_lds16(Bg1 + k0, &Bsl[nb][lo1]);
            load_lds16(Bg2 + k0, &Bsl[nb][lo2]);
            asm volatile("s_waitcnt vmcnt(5)" ::: "memory");   // cur tile done, prefetch in flight
        } else {
            asm volatile("s_waitcnt vmcnt(0)" ::: "memory");
        }
        __builtin_amdgcn_s_barrier();
        f16x8 af[4], bf[6];
        #pragma unroll
        for (int j = 0; j < 4; j++)
            af[j] = *(const f16x8*)&Asl[cur][(64 * wm + 16 * j + l16) * 32 + fs * 8];
        #pragma unroll
        for (int j = 0; j < 6; j++)
            bf[j] = *(const f16x8*)&Bsl[cur][(96 * wn + 16 * j + l16) * 32 + fs * 8];
        #pragma unroll
        for (int mi = 0; mi < 4; mi++)
            #pragma unroll
            for (int ni = 0; ni < 6; ni++)
                acc[mi][ni] = MFMA16(af[mi], bf[ni], acc[mi][ni]);
    }

    float s = 0.f;
    if (MODE == 1 || MODE == 3) s = e.sA[0] * e.sB[0];
    #pragma unroll
    for (int mi = 0; mi < 4; mi++)
        #pragma unroll
        for (int ni = 0; ni < 6; ni++)
            epi_store<MODE>(e, s, acc[mi][ni],
                            m0 + 64 * wm + 16 * mi + quad * 4,
                            n0 + 96 * wn + 16 * ni + l16);
}

// ---------------------------------------------------------------- GEMM NT 128x128 (short-K)
// Used for Wo (K=256, MODE 1) and Wup (K=512, MODE 3): 1024 blocks = 4/CU.
// MODE 1 additionally reduces per-row sum(x2^2) (LDS tree + 1 atomic/row).
template <int MODE>
__global__ __launch_bounds__(256) void gemm_nt(const f16* __restrict__ A,
                                               const f16* __restrict__ Bm,
                                               int K, GemmEpi e) {
    __shared__ f16 Asl[2][128 * 32];
    __shared__ f16 Bsl[2][128 * 32];
    int tid = threadIdx.x;
    int lane = tid & 63, wv = tid >> 6;
    int wm = wv >> 1, wn = wv & 1;
    int quad = lane >> 4, l16 = lane & 15;
    int m0 = blockIdx.x * 128, n0 = blockIdx.y * 128;
    f32x4 acc[4][4] = {};

    int srow = lane >> 2;
    int scg = (lane & 3) ^ ((lane >> 3) & 3);
    const f16* Ag0 = &A[(size_t)(m0 + 16 * wv + srow) * K + scg * 8];
    const f16* Ag1 = &A[(size_t)(m0 + 16 * (wv + 4) + srow) * K + scg * 8];
    const f16* Bg0 = &Bm[(size_t)(n0 + 16 * wv + srow) * K + scg * 8];
    const f16* Bg1 = &Bm[(size_t)(n0 + 16 * (wv + 4) + srow) * K + scg * 8];
    int lo0 = (16 * wv) * 32, lo1 = (16 * (wv + 4)) * 32;

    int fs = quad ^ ((l16 >> 1) & 3);
    int niter = K >> 5;

    load_lds16(Ag0, &Asl[0][lo0]);
    load_lds16(Ag1, &Asl[0][lo1]);
    load_lds16(Bg0, &Bsl[0][lo0]);
    load_lds16(Bg1, &Bsl[0][lo1]);

    for (int i = 0; i < niter; i++) {
        int cur = i & 1;
        __builtin_amdgcn_s_barrier();
        if (i + 1 < niter) {
            int k0 = (i + 1) << 5;
            int nb = cur ^ 1;
            load_lds16(Ag0 + k0, &Asl[nb][lo0]);
            load_lds16(Ag1 + k0, &Asl[nb][lo1]);
            load_lds16(Bg0 + k0, &Bsl[nb][lo0]);
            load_lds16(Bg1 + k0, &Bsl[nb][lo1]);
            asm volatile("s_waitcnt vmcnt(4)" ::: "memory");
        } else {
            asm volatile("s_waitcnt vmcnt(0)" ::: "memory");
        }
        __builtin_amdgcn_s_barrier();
        f16x8 af[4], bf[4];
        #pragma unroll
        for (int j = 0; j < 4; j++)
            af[j] = *(const f16x8*)&Asl[cur][(64 * wm + 16 * j + l16) * 32 + fs * 8];
        #pragma unroll
        for (int j = 0; j < 4; j++)
            bf[j] = *(const f16x8*)&Bsl[cur][(64 * wn + 16 * j + l16) * 32 + fs * 8];
        #pragma unroll
        for (int mi = 0; mi < 4; mi++)
            #pragma unroll
            for (int ni = 0; ni < 4; ni++)
                acc[mi][ni] = MFMA16(af[mi], bf[ni], acc[mi][ni]);
    }

    float s = 0.f;
    if (MODE == 1 || MODE == 3) s = e.sA[0] * e.sB[0];

    if constexpr (MODE == 1) {
        // fused epilogue: write x2 = x + s*vv AND accumulate per-row sum(x2^2).
        float* rbuf = (float*)&Asl[0][0];   // 16 KiB (reuse staging LDS)
        __syncthreads();                    // all K-loop LDS reads retired
        #pragma unroll
        for (int mi = 0; mi < 4; mi++) {
            #pragma unroll
            for (int i = 0; i < 4; i++) {
                int rl = 64 * wm + 16 * mi + quad * 4 + i;
                int gm = m0 + rl;
                float p = 0.f;
                #pragma unroll
                for (int ni = 0; ni < 4; ni++) {
                    int gn = n0 + 64 * wn + 16 * ni + l16;
                    size_t o = (size_t)gm * V + gn;
                    float val = e.residf[o] + s * acc[mi][ni][i];
                    e.outh[o] = (f16)val;
                    p += val * val;
                }
                rbuf[rl * 32 + wn * 16 + l16] = p;
            }
        }
        __syncthreads();
        if (tid < 128) {
            float tot = 0.f;
            #pragma unroll
            for (int j = 0; j < 32; j++) tot += rbuf[tid * 32 + j];
            atomicAdd(&e.rowss[m0 + tid], tot);
        }
    } else {
        #pragma unroll
        for (int mi = 0; mi < 4; mi++)
            #pragma unroll
            for (int ni = 0; ni < 4; ni++)
                epi_store<MODE>(e, s, acc[mi][ni],
                                m0 + 64 * wm + 16 * mi + quad * 4,
                                n0 + 64 * wn + 16 * ni + l16);
    }
}

// ---------------------------------------------------------------- GEMM NT (BK=64, long-K)
// Wdown (K=2048, MODE 2): 256 blocks exactly; 128x128 has no intensity
// headroom at grid>=256 for N=512, so this stays the fastest known config.
template <int MODE>
__global__ __launch_bounds__(256) void gemm_nt_k64(const f16* __restrict__ A,
                                                   const f16* __restrict__ Bm,
                                                   int K, GemmEpi e) {
    __shared__ f16 Asl[2][128 * 64];
    __shared__ f16 Bsl[2][128 * 64];
    int tid = threadIdx.x;
    int lane = tid & 63, wv = tid >> 6;
    int wm = wv >> 1, wn = wv & 1;
    int quad = lane >> 4, l16 = lane & 15;
    int m0 = blockIdx.x * 128, n0 = blockIdx.y * 128;
    f32x4 acc[4][4] = {};

    int r8 = lane >> 3;
    int gcol = (lane & 7) ^ r8;
    const f16* Ag[4]; const f16* Bg[4]; int lo[4];
    #pragma unroll
    for (int j = 0; j < 4; j++) {
        int rbase = 8 * (wv + 4 * j);
        Ag[j] = &A[(size_t)(m0 + rbase + r8) * K + gcol * 8];
        Bg[j] = &Bm[(size_t)(n0 + rbase + r8) * K + gcol * 8];
        lo[j] = rbase * 64;
    }
    int niter = K >> 6;

    #pragma unroll
    for (int j = 0; j < 4; j++) {
        load_lds16(Ag[j], &Asl[0][lo[j]]);
        load_lds16(Bg[j], &Bsl[0][lo[j]]);
    }

    for (int i = 0; i < niter; i++) {
        int cur = i & 1;
        __builtin_amdgcn_s_barrier();
        if (i + 1 < niter) {
            int k0 = (i + 1) << 6;
            int nb = cur ^ 1;
            #pragma unroll
            for (int j = 0; j < 4; j++) {
                load_lds16(Ag[j] + k0, &Asl[nb][lo[j]]);
                load_lds16(Bg[j] + k0, &Bsl[nb][lo[j]]);
            }
            asm volatile("s_waitcnt vmcnt(8)" ::: "memory");
        } else {
            asm volatile("s_waitcnt vmcnt(0)" ::: "memory");
        }
        __builtin_amdgcn_s_barrier();
        #pragma unroll
        for (int kk = 0; kk < 2; kk++) {
            f16x8 af[4], bf[4];
            #pragma unroll
            for (int j = 0; j < 4; j++) {
                int row = 64 * wm + 16 * j + l16;
                int sl = (kk * 4 + quad) ^ (l16 & 7);
                af[j] = *(const f16x8*)&Asl[cur][row * 64 + sl * 8];
            }
            #pragma unroll
            for (int j = 0; j < 4; j++) {
                int row = 64 * wn + 16 * j + l16;
                int sl = (kk * 4 + quad) ^ (l16 & 7);
                bf[j] = *(const f16x8*)&Bsl[cur][row * 64 + sl * 8];
            }
            #pragma unroll
            for (int mi = 0; mi < 4; mi++)
                #pragma unroll
                for (int ni = 0; ni < 4; ni++)
                    acc[mi][ni] = MFMA16(af[mi], bf[ni], acc[mi][ni]);
        }
    }

    float s = 0.f;
    if (MODE == 1 || MODE == 3) s = e.sA[0] * e.sB[0];
    #pragma unroll
    for (int mi = 0; mi < 4; mi++)
        #pragma unroll
        for (int ni = 0; ni < 4; ni++)
            epi_store<MODE>(e, s, acc[mi][ni],
                            m0 + 64 * wm + 16 * mi + quad * 4,
                            n0 + 64 * wn + 16 * ni + l16);
}

// ---------------------------------------------------------------- attention
// retrieved[t,d] = sum_{s>t} decay^(s-t-1) * (q_t . k_s) * v[s,d]
// grid: (T/32, B) = 256 blocks; block 256 (4 waves), QBLK=32.
// Decay-window truncation: tiles with max weight < 2^-25 contribute < ~1e-5.
__global__ __launch_bounds__(256) void attn_kernel(const f16* __restrict__ q,
                                                   const f16* __restrict__ k,
                                                   const f16* __restrict__ vT,
                                                   f16* __restrict__ ret,
                                                   const float* __restrict__ decay_logit) {
    __shared__ f16 Psl[32 * 72];
    int tid = threadIdx.x, lane = tid & 63, wv = tid >> 6;
    int quad = lane >> 4, l16 = lane & 15;
    int b = blockIdx.y, t0 = blockIdx.x * 32;
    const f16* qb = q + (size_t)b * T * D;
    const f16* kb = k + (size_t)b * T * D;
    const f16* vb = vT + (size_t)b * D * T;
    f16* rb = ret + (size_t)b * T * D;

    float dl = decay_logit[0];
    float decay = 1.f / (1.f + expf(-dl));
    float l2d = log2f(decay);
    float nl2d = -l2d;

    f16x8 qf[2][8];
    #pragma unroll
    for (int mi = 0; mi < 2; mi++)
        #pragma unroll
        for (int kk = 0; kk < 8; kk++)
            qf[mi][kk] = *(const f16x8*)&qb[(size_t)(t0 + 16 * mi + l16) * D + kk * 32 + quad * 8];

    f32x4 acc2[2][4] = {};

    for (int s0 = t0; s0 < T; s0 += 64) {
        if ((float)(s0 - t0 - 32) * nl2d > 25.f) break;
        int srow = s0 + 16 * wv + l16;
        int srcl = srow < T ? srow : T - 1;
        f32x4 sacc[2] = {};
        #pragma unroll
        for (int kk = 0; kk < 8; kk++) {
            f16x8 bf = *(const f16x8*)&kb[(size_t)srcl * D + kk * 32 + quad * 8];
            sacc[0] = MFMA16(qf[0][kk], bf, sacc[0]);
            sacc[1] = MFMA16(qf[1][kk], bf, sacc[1]);
        }
        __syncthreads();
        #pragma unroll
        for (int mi = 0; mi < 2; mi++) {
            #pragma unroll
            for (int i = 0; i < 4; i++) {
                int t_ = t0 + 16 * mi + quad * 4 + i;
                int diff = srow - t_;
                float w = (diff > 0 && srow < T) ? exp2f((float)(diff - 1) * l2d) : 0.f;
                Psl[(16 * mi + quad * 4 + i) * 72 + 16 * wv + l16] = (f16)(sacc[mi][i] * w);
            }
        }
        __syncthreads();
        #pragma unroll
        for (int kk = 0; kk < 2; kk++) {
            int sb = s0 + kk * 32 + quad * 8;
            if (sb >= T) sb = T - 8;
            f16x8 pa[2], vf[4];
            #pragma unroll
            for (int mi = 0; mi < 2; mi++)
                pa[mi] = *(const f16x8*)&Psl[(16 * mi + l16) * 72 + kk * 32 + quad * 8];
            #pragma unroll
            for (int ni = 0; ni < 4; ni++)
                vf[ni] = *(const f16x8*)&vb[(size_t)(64 * wv + 16 * ni + l16) * T + sb];
            #pragma unroll
            for (int mi = 0; mi < 2; mi++)
                #pragma unroll
                for (int ni = 0; ni < 4; ni++)
                    acc2[mi][ni] = MFMA16(pa[mi], vf[ni], acc2[mi][ni]);
        }
    }

    #pragma unroll
    for (int mi = 0; mi < 2; mi++) {
        #pragma unroll
        for (int ni = 0; ni < 4; ni++) {
            int t_ = t0 + 16 * mi + quad * 4;
            int d_ = 64 * wv + 16 * ni + l16;
            #pragma unroll
            for (int i = 0; i < 4; i++)
                rb[(size_t)(t_ + i) * D + d_] = (f16)acc2[mi][ni][i];
        }
    }
}

// ---------------------------------------------------------------- launch
extern "C" void kernel_launch(void* const* d_in, const int* in_sizes, int n_in,
                              void* d_out, int out_size, void* d_ws, size_t ws_size,
                              hipStream_t stream) {
    const float* x           = (const float*)d_in[0];
    const float* Wq          = (const float*)d_in[1];
    const float* Wk          = (const float*)d_in[2];
    const float* Wv          = (const float*)d_in[3];
    const float* Wo          = (const float*)d_in[4];
    const float* decay_logit = (const float*)d_in[5];
    const float* q_out_scale = (const float*)d_in[6];
    const float* Wdown       = (const float*)d_in[7];
    const float* Wup         = (const float*)d_in[8];
    const float* t_bias      = (const float*)d_in[9];
    const float* t_out_scale = (const float*)d_in[10];
    const float* q_scale     = (const float*)d_in[11];
    const float* t_scale     = (const float*)d_in[12];

    char* ws = (char*)d_ws;
    f16* Wqkv16  = (f16*)ws;  ws += (size_t)768 * V * 2;       // 3 MiB  } contiguous
    f16* Wo16    = (f16*)ws;  ws += (size_t)V * D * 2;         // 1 MiB  } dst for
    f16* Wdown16 = (f16*)ws;  ws += (size_t)R * V * 2;         // 2 MiB  } prep conv
    f16* Wup16   = (f16*)ws;  ws += (size_t)V * R * 2;         // 2 MiB  }
    f16* xn16    = (f16*)ws;  ws += (size_t)M * V * 2;         // 32 MiB (rmsnorm(x) f16)
    f16* q16     = (f16*)ws;  ws += (size_t)M * D * 2;         // 4 MiB (reused by h16)
    f16* k16     = (f16*)ws;  ws += (size_t)M * D * 2;         // 4 MiB (reused by h16)
    f16* vT16    = (f16*)ws;  ws += (size_t)Bsz * D * T * 2;   // 4 MiB
    f16* ret16   = (f16*)ws;  ws += (size_t)M * D * 2;         // 4 MiB
    f16* x2_16   = (f16*)ws;  ws += (size_t)M * V * 2;         // 32 MiB (residual stream, f16)
    float* rowss = (float*)ws; ws += (size_t)M * 4;            // 32 KiB (sum x2^2 per row)
    f16* h16     = q16;  // reuse q16+k16 region (8 MiB) after attention

    float* out = (float*)d_out;

    // 1. prep: weight conversion + rmsnorm(x) + rowss zeroing, one launch
    prep_kernel<<<dim3(12288), 256, 0, stream>>>(Wq, Wk, Wv, Wo, Wdown, Wup,
                                                 Wqkv16, x, xn16, rowss);

    // 2. QKV GEMM (fused, N=768), K=2048: 128x192 tile -> 256 blocks, 76.8 FLOP/B
    {
        GemmEpi e = {};
        e.out_q = q16; e.out_k = k16; e.out_vT = vT16;
        gemm_nt_192<0><<<dim3(M / 128, 768 / 192), 256, 0, stream>>>(xn16, Wqkv16, V, e);
    }

    // 3. fused decay-attention -> ret16
    attn_kernel<<<dim3(T / 32, Bsz), 256, 0, stream>>>(q16, k16, vT16, ret16, decay_logit);

    // 4. Wo GEMM + residual + row-ss: x2 = x + qs*qos*(ret @ Wo^T), rowss += x2^2
    {
        GemmEpi e = {};
        e.residf = x; e.outh = x2_16; e.sA = q_scale; e.sB = q_out_scale;
        e.rowss = rowss;
        gemm_nt<1><<<dim3(M / 128, V / 128), 256, 0, stream>>>(ret16, Wo16, D, e);
    }

    // 5. Wdown GEMM on RAW x2 + per-row rms scale + bias + exact gelu -> h16
    {
        GemmEpi e = {};
        e.out_h = h16; e.bias = t_bias; e.rowss = rowss;
        gemm_nt_k64<2><<<dim3(M / 128, R / 128), 256, 0, stream>>>(x2_16, Wdown16, V, e);
    }

    // 6. Wup GEMM + residual: out (fp32) = x2 + ts*tos*(h @ Wup^T)  (K=512)
    {
        GemmEpi e = {};
        e.residh = x2_16; e.outf = out; e.sA = t_scale; e.sB = t_out_scale;
        gemm_nt<3><<<dim3(M / 128, V / 128), 256, 0, stream>>>(h16, Wup16, R, e);
    }
}

// Round 11
// 299.362 us; speedup vs baseline: 1.1016x; 1.0143x over previous
//
#include <hip/hip_runtime.h>
#include <cmath>

typedef _Float16 f16;
typedef _Float16 f16x8 __attribute__((ext_vector_type(8)));
typedef _Float16 f16x4 __attribute__((ext_vector_type(4)));
typedef float f32x4 __attribute__((ext_vector_type(4)));

#define MFMA16(a, b, c) __builtin_amdgcn_mfma_f32_16x16x32_f16(a, b, c, 0, 0, 0)

static constexpr int Bsz = 4;
static constexpr int T = 2048;
static constexpr int V = 2048;
static constexpr int D = 256;
static constexpr int R = 512;
static constexpr int M = Bsz * T;   // 8192

// async global->LDS, 16B per lane; LDS dest = wave-uniform base + lane*16
__device__ __forceinline__ void load_lds16(const f16* g, f16* l) {
    __builtin_amdgcn_global_load_lds(
        (const __attribute__((address_space(1))) unsigned int*)(unsigned long long)g,
        (__attribute__((address_space(3))) unsigned int*)(unsigned int)(unsigned long long)l,
        16, 0, 0);
}

// ---------------------------------------------------------------- prep
// One launch: blocks [0,4096) convert the 6 weight matrices to f16;
// blocks [4096,12288) rmsnorm x -> xn16 (f16) and zero rowss[row].
__global__ __launch_bounds__(256) void prep_kernel(const float* __restrict__ s0,
                                                   const float* __restrict__ s1,
                                                   const float* __restrict__ s2,
                                                   const float* __restrict__ s3,
                                                   const float* __restrict__ s4,
                                                   const float* __restrict__ s5,
                                                   f16* __restrict__ dst,
                                                   const float* __restrict__ x,
                                                   f16* __restrict__ xn,
                                                   float* __restrict__ rowss) {
    int bid = blockIdx.x;
    int tid = threadIdx.x;
    if (bid < 4096) {
        int idx = (bid * 256 + tid) * 4;
        const float* src; int off;
        if      (idx <  524288) { src = s0; off = idx; }
        else if (idx < 1048576) { src = s1; off = idx - 524288; }
        else if (idx < 1572864) { src = s2; off = idx - 1048576; }
        else if (idx < 2097152) { src = s3; off = idx - 1572864; }
        else if (idx < 3145728) { src = s4; off = idx - 2097152; }
        else                    { src = s5; off = idx - 3145728; }
        float4 v = *(const float4*)&src[off];
        f16x4 o;
        o[0] = (f16)v.x; o[1] = (f16)v.y; o[2] = (f16)v.z; o[3] = (f16)v.w;
        *(f16x4*)&dst[idx] = o;
        return;
    }
    int row = bid - 4096;
    const float* xr = x + (size_t)row * V;
    float4 v0 = ((const float4*)xr)[tid];
    float4 v1 = ((const float4*)xr)[tid + 256];
    float ss = v0.x * v0.x + v0.y * v0.y + v0.z * v0.z + v0.w * v0.w
             + v1.x * v1.x + v1.y * v1.y + v1.z * v1.z + v1.w * v1.w;
    #pragma unroll
    for (int o = 32; o > 0; o >>= 1) ss += __shfl_xor(ss, o);
    __shared__ float wsum[4];
    if ((tid & 63) == 0) wsum[tid >> 6] = ss;
    __syncthreads();
    float tot = wsum[0] + wsum[1] + wsum[2] + wsum[3];
    float s = rsqrtf(tot / (float)V + 1.1920929e-07f);
    f16* orow = xn + (size_t)row * V;
    f16x4 o0, o1;
    o0[0] = (f16)(v0.x * s); o0[1] = (f16)(v0.y * s);
    o0[2] = (f16)(v0.z * s); o0[3] = (f16)(v0.w * s);
    o1[0] = (f16)(v1.x * s); o1[1] = (f16)(v1.y * s);
    o1[2] = (f16)(v1.z * s); o1[3] = (f16)(v1.w * s);
    *(f16x4*)&orow[tid * 4] = o0;
    *(f16x4*)&orow[1024 + tid * 4] = o1;
    if (tid == 0) rowss[row] = 0.f;     // zero accumulator for Wo's row-ss
}

// ---------------------------------------------------------------- GEMM epilogue params
struct GemmEpi {
    const float* residf;
    const f16* residh;
    float* outf;
    f16* outh;
    f16* out_q; f16* out_k; f16* out_vT;
    f16* out_h;
    const float* bias;
    const float* sA; const float* sB;
    float* rowss;          // MODE 1: accumulate per-row sum(x2^2); MODE 2: read
};

// Epilogue store for one 16-row fragment group.
// MODE 2 applies the factored-out rmsnorm scale s[gm] = rsqrt(rowss/V + eps)
// BEFORE bias+gelu (rms(x2) @ W^T == s[m] * (x2 @ W^T)).
template <int MODE>
__device__ __forceinline__ void epi_store(const GemmEpi& e, float s, f32x4 a,
                                          int gm_base, int gn) {
    #pragma unroll
    for (int i = 0; i < 4; i++) {
        int gm = gm_base + i;
        float vv = a[i];
        if (MODE == 0) {
            if (gn < 256) {
                e.out_q[(size_t)gm * D + gn] = (f16)vv;
            } else if (gn < 512) {
                e.out_k[(size_t)gm * D + (gn - 256)] = (f16)vv;
            } else {
                int d = gn - 512;
                int b = gm >> 11, t = gm & 2047;
                e.out_vT[((size_t)b * D + d) * T + t] = (f16)vv;
            }
        } else if (MODE == 1) {
            size_t o = (size_t)gm * V + gn;
            e.outh[o] = (f16)(e.residf[o] + s * vv);
        } else if (MODE == 2) {
            float sc = rsqrtf(e.rowss[gm] * (1.f / 2048.f) + 1.1920929e-07f);
            float z = sc * vv + e.bias[gn];
            float g = 0.5f * z * (1.f + erff(z * 0.70710678118654752f));
            e.out_h[(size_t)gm * R + gn] = (f16)g;
        } else {
            size_t o = (size_t)gm * V + gn;
            e.outf[o] = (float)e.residh[o] + s * vv;
        }
    }
}

// ---------------------------------------------------------------- GEMM NT 128x128 (short-K)
// Used for Wo (K=256, MODE 1) and Wup (K=512, MODE 3): 1024 blocks = 4/CU.
// MODE 1 additionally reduces per-row sum(x2^2) (LDS tree + 1 atomic/row).
template <int MODE>
__global__ __launch_bounds__(256) void gemm_nt(const f16* __restrict__ A,
                                               const f16* __restrict__ Bm,
                                               int K, GemmEpi e) {
    __shared__ f16 Asl[2][128 * 32];
    __shared__ f16 Bsl[2][128 * 32];
    int tid = threadIdx.x;
    int lane = tid & 63, wv = tid >> 6;
    int wm = wv >> 1, wn = wv & 1;
    int quad = lane >> 4, l16 = lane & 15;
    int m0 = blockIdx.x * 128, n0 = blockIdx.y * 128;
    f32x4 acc[4][4] = {};

    int srow = lane >> 2;
    int scg = (lane & 3) ^ ((lane >> 3) & 3);
    const f16* Ag0 = &A[(size_t)(m0 + 16 * wv + srow) * K + scg * 8];
    const f16* Ag1 = &A[(size_t)(m0 + 16 * (wv + 4) + srow) * K + scg * 8];
    const f16* Bg0 = &Bm[(size_t)(n0 + 16 * wv + srow) * K + scg * 8];
    const f16* Bg1 = &Bm[(size_t)(n0 + 16 * (wv + 4) + srow) * K + scg * 8];
    int lo0 = (16 * wv) * 32, lo1 = (16 * (wv + 4)) * 32;

    int fs = quad ^ ((l16 >> 1) & 3);
    int niter = K >> 5;

    load_lds16(Ag0, &Asl[0][lo0]);
    load_lds16(Ag1, &Asl[0][lo1]);
    load_lds16(Bg0, &Bsl[0][lo0]);
    load_lds16(Bg1, &Bsl[0][lo1]);

    for (int i = 0; i < niter; i++) {
        int cur = i & 1;
        __builtin_amdgcn_s_barrier();
        if (i + 1 < niter) {
            int k0 = (i + 1) << 5;
            int nb = cur ^ 1;
            load_lds16(Ag0 + k0, &Asl[nb][lo0]);
            load_lds16(Ag1 + k0, &Asl[nb][lo1]);
            load_lds16(Bg0 + k0, &Bsl[nb][lo0]);
            load_lds16(Bg1 + k0, &Bsl[nb][lo1]);
            asm volatile("s_waitcnt vmcnt(4)" ::: "memory");
        } else {
            asm volatile("s_waitcnt vmcnt(0)" ::: "memory");
        }
        __builtin_amdgcn_s_barrier();
        f16x8 af[4], bf[4];
        #pragma unroll
        for (int j = 0; j < 4; j++)
            af[j] = *(const f16x8*)&Asl[cur][(64 * wm + 16 * j + l16) * 32 + fs * 8];
        #pragma unroll
        for (int j = 0; j < 4; j++)
            bf[j] = *(const f16x8*)&Bsl[cur][(64 * wn + 16 * j + l16) * 32 + fs * 8];
        #pragma unroll
        for (int mi = 0; mi < 4; mi++)
            #pragma unroll
            for (int ni = 0; ni < 4; ni++)
                acc[mi][ni] = MFMA16(af[mi], bf[ni], acc[mi][ni]);
    }

    float s = 0.f;
    if (MODE == 1 || MODE == 3) s = e.sA[0] * e.sB[0];

    if constexpr (MODE == 1) {
        // fused epilogue: write x2 = x + s*vv AND accumulate per-row sum(x2^2).
        float* rbuf = (float*)&Asl[0][0];   // 16 KiB (reuse staging LDS)
        __syncthreads();                    // all K-loop LDS reads retired
        #pragma unroll
        for (int mi = 0; mi < 4; mi++) {
            #pragma unroll
            for (int i = 0; i < 4; i++) {
                int rl = 64 * wm + 16 * mi + quad * 4 + i;
                int gm = m0 + rl;
                float p = 0.f;
                #pragma unroll
                for (int ni = 0; ni < 4; ni++) {
                    int gn = n0 + 64 * wn + 16 * ni + l16;
                    size_t o = (size_t)gm * V + gn;
                    float val = e.residf[o] + s * acc[mi][ni][i];
                    e.outh[o] = (f16)val;
                    p += val * val;
                }
                rbuf[rl * 32 + wn * 16 + l16] = p;
            }
        }
        __syncthreads();
        if (tid < 128) {
            float tot = 0.f;
            #pragma unroll
            for (int j = 0; j < 32; j++) tot += rbuf[tid * 32 + j];
            atomicAdd(&e.rowss[m0 + tid], tot);
        }
    } else {
        #pragma unroll
        for (int mi = 0; mi < 4; mi++)
            #pragma unroll
            for (int ni = 0; ni < 4; ni++)
                epi_store<MODE>(e, s, acc[mi][ni],
                                m0 + 64 * wm + 16 * mi + quad * 4,
                                n0 + 64 * wn + 16 * ni + l16);
    }
}

// ---------------------------------------------------------------- GEMM NT (BK=64, long-K)
// QKV (MODE 0) and Wdown (MODE 2), K=2048. Measured-best long-K config across
// 11 structural variants (rounds 0-10): 43.4us QKV. 128x128 tile, BK=64 (two
// K=32 sub-tiles per barrier-pair), 64 KiB LDS -> 2 blocks/CU (the staging-
// concurrency sweet spot: r10's 1 blk/CU at +20% intensity was NET SLOWER).
// Swizzle: LDS[r][s] holds colgroup s^(r&7); source lane addr pre-swizzled.
template <int MODE>
__global__ __launch_bounds__(256) void gemm_nt_k64(const f16* __restrict__ A,
                                                   const f16* __restrict__ Bm,
                                                   int K, GemmEpi e) {
    __shared__ f16 Asl[2][128 * 64];
    __shared__ f16 Bsl[2][128 * 64];
    int tid = threadIdx.x;
    int lane = tid & 63, wv = tid >> 6;
    int wm = wv >> 1, wn = wv & 1;
    int quad = lane >> 4, l16 = lane & 15;
    int m0 = blockIdx.x * 128, n0 = blockIdx.y * 128;
    f32x4 acc[4][4] = {};

    int r8 = lane >> 3;
    int gcol = (lane & 7) ^ r8;
    const f16* Ag[4]; const f16* Bg[4]; int lo[4];
    #pragma unroll
    for (int j = 0; j < 4; j++) {
        int rbase = 8 * (wv + 4 * j);
        Ag[j] = &A[(size_t)(m0 + rbase + r8) * K + gcol * 8];
        Bg[j] = &Bm[(size_t)(n0 + rbase + r8) * K + gcol * 8];
        lo[j] = rbase * 64;
    }
    int niter = K >> 6;

    #pragma unroll
    for (int j = 0; j < 4; j++) {
        load_lds16(Ag[j], &Asl[0][lo[j]]);
        load_lds16(Bg[j], &Bsl[0][lo[j]]);
    }

    for (int i = 0; i < niter; i++) {
        int cur = i & 1;
        __builtin_amdgcn_s_barrier();
        if (i + 1 < niter) {
            int k0 = (i + 1) << 6;
            int nb = cur ^ 1;
            #pragma unroll
            for (int j = 0; j < 4; j++) {
                load_lds16(Ag[j] + k0, &Asl[nb][lo[j]]);
                load_lds16(Bg[j] + k0, &Bsl[nb][lo[j]]);
            }
            asm volatile("s_waitcnt vmcnt(8)" ::: "memory");
        } else {
            asm volatile("s_waitcnt vmcnt(0)" ::: "memory");
        }
        __builtin_amdgcn_s_barrier();
        #pragma unroll
        for (int kk = 0; kk < 2; kk++) {
            f16x8 af[4], bf[4];
            #pragma unroll
            for (int j = 0; j < 4; j++) {
                int row = 64 * wm + 16 * j + l16;
                int sl = (kk * 4 + quad) ^ (l16 & 7);
                af[j] = *(const f16x8*)&Asl[cur][row * 64 + sl * 8];
            }
            #pragma unroll
            for (int j = 0; j < 4; j++) {
                int row = 64 * wn + 16 * j + l16;
                int sl = (kk * 4 + quad) ^ (l16 & 7);
                bf[j] = *(const f16x8*)&Bsl[cur][row * 64 + sl * 8];
            }
            #pragma unroll
            for (int mi = 0; mi < 4; mi++)
                #pragma unroll
                for (int ni = 0; ni < 4; ni++)
                    acc[mi][ni] = MFMA16(af[mi], bf[ni], acc[mi][ni]);
        }
    }

    float s = 0.f;
    if (MODE == 1 || MODE == 3) s = e.sA[0] * e.sB[0];
    #pragma unroll
    for (int mi = 0; mi < 4; mi++)
        #pragma unroll
        for (int ni = 0; ni < 4; ni++)
            epi_store<MODE>(e, s, acc[mi][ni],
                            m0 + 64 * wm + 16 * mi + quad * 4,
                            n0 + 64 * wn + 16 * ni + l16);
}

// ---------------------------------------------------------------- attention
// retrieved[t,d] = sum_{s>t} decay^(s-t-1) * (q_t . k_s) * v[s,d]
// grid: (T/32, B) = 256 blocks; block 256 (4 waves), QBLK=32.
// Decay-window truncation: tiles with max weight < 2^-25 contribute < ~1e-5.
__global__ __launch_bounds__(256) void attn_kernel(const f16* __restrict__ q,
                                                   const f16* __restrict__ k,
                                                   const f16* __restrict__ vT,
                                                   f16* __restrict__ ret,
                                                   const float* __restrict__ decay_logit) {
    __shared__ f16 Psl[32 * 72];
    int tid = threadIdx.x, lane = tid & 63, wv = tid >> 6;
    int quad = lane >> 4, l16 = lane & 15;
    int b = blockIdx.y, t0 = blockIdx.x * 32;
    const f16* qb = q + (size_t)b * T * D;
    const f16* kb = k + (size_t)b * T * D;
    const f16* vb = vT + (size_t)b * D * T;
    f16* rb = ret + (size_t)b * T * D;

    float dl = decay_logit[0];
    float decay = 1.f / (1.f + expf(-dl));
    float l2d = log2f(decay);
    float nl2d = -l2d;

    f16x8 qf[2][8];
    #pragma unroll
    for (int mi = 0; mi < 2; mi++)
        #pragma unroll
        for (int kk = 0; kk < 8; kk++)
            qf[mi][kk] = *(const f16x8*)&qb[(size_t)(t0 + 16 * mi + l16) * D + kk * 32 + quad * 8];

    f32x4 acc2[2][4] = {};

    for (int s0 = t0; s0 < T; s0 += 64) {
        if ((float)(s0 - t0 - 32) * nl2d > 25.f) break;
        int srow = s0 + 16 * wv + l16;
        int srcl = srow < T ? srow : T - 1;
        f32x4 sacc[2] = {};
        #pragma unroll
        for (int kk = 0; kk < 8; kk++) {
            f16x8 bf = *(const f16x8*)&kb[(size_t)srcl * D + kk * 32 + quad * 8];
            sacc[0] = MFMA16(qf[0][kk], bf, sacc[0]);
            sacc[1] = MFMA16(qf[1][kk], bf, sacc[1]);
        }
        __syncthreads();
        #pragma unroll
        for (int mi = 0; mi < 2; mi++) {
            #pragma unroll
            for (int i = 0; i < 4; i++) {
                int t_ = t0 + 16 * mi + quad * 4 + i;
                int diff = srow - t_;
                float w = (diff > 0 && srow < T) ? exp2f((float)(diff - 1) * l2d) : 0.f;
                Psl[(16 * mi + quad * 4 + i) * 72 + 16 * wv + l16] = (f16)(sacc[mi][i] * w);
            }
        }
        __syncthreads();
        #pragma unroll
        for (int kk = 0; kk < 2; kk++) {
            int sb = s0 + kk * 32 + quad * 8;
            if (sb >= T) sb = T - 8;
            f16x8 pa[2], vf[4];
            #pragma unroll
            for (int mi = 0; mi < 2; mi++)
                pa[mi] = *(const f16x8*)&Psl[(16 * mi + l16) * 72 + kk * 32 + quad * 8];
            #pragma unroll
            for (int ni = 0; ni < 4; ni++)
                vf[ni] = *(const f16x8*)&vb[(size_t)(64 * wv + 16 * ni + l16) * T + sb];
            #pragma unroll
            for (int mi = 0; mi < 2; mi++)
                #pragma unroll
                for (int ni = 0; ni < 4; ni++)
                    acc2[mi][ni] = MFMA16(pa[mi], vf[ni], acc2[mi][ni]);
        }
    }

    #pragma unroll
    for (int mi = 0; mi < 2; mi++) {
        #pragma unroll
        for (int ni = 0; ni < 4; ni++) {
            int t_ = t0 + 16 * mi + quad * 4;
            int d_ = 64 * wv + 16 * ni + l16;
            #pragma unroll
            for (int i = 0; i < 4; i++)
                rb[(size_t)(t_ + i) * D + d_] = (f16)acc2[mi][ni][i];
        }
    }
}

// ---------------------------------------------------------------- launch
extern "C" void kernel_launch(void* const* d_in, const int* in_sizes, int n_in,
                              void* d_out, int out_size, void* d_ws, size_t ws_size,
                              hipStream_t stream) {
    const float* x           = (const float*)d_in[0];
    const float* Wq          = (const float*)d_in[1];
    const float* Wk          = (const float*)d_in[2];
    const float* Wv          = (const float*)d_in[3];
    const float* Wo          = (const float*)d_in[4];
    const float* decay_logit = (const float*)d_in[5];
    const float* q_out_scale = (const float*)d_in[6];
    const float* Wdown       = (const float*)d_in[7];
    const float* Wup         = (const float*)d_in[8];
    const float* t_bias      = (const float*)d_in[9];
    const float* t_out_scale = (const float*)d_in[10];
    const float* q_scale     = (const float*)d_in[11];
    const float* t_scale     = (const float*)d_in[12];

    char* ws = (char*)d_ws;
    f16* Wqkv16  = (f16*)ws;  ws += (size_t)768 * V * 2;       // 3 MiB  } contiguous
    f16* Wo16    = (f16*)ws;  ws += (size_t)V * D * 2;         // 1 MiB  } dst for
    f16* Wdown16 = (f16*)ws;  ws += (size_t)R * V * 2;         // 2 MiB  } prep conv
    f16* Wup16   = (f16*)ws;  ws += (size_t)V * R * 2;         // 2 MiB  }
    f16* xn16    = (f16*)ws;  ws += (size_t)M * V * 2;         // 32 MiB (rmsnorm(x) f16)
    f16* q16     = (f16*)ws;  ws += (size_t)M * D * 2;         // 4 MiB (reused by h16)
    f16* k16     = (f16*)ws;  ws += (size_t)M * D * 2;         // 4 MiB (reused by h16)
    f16* vT16    = (f16*)ws;  ws += (size_t)Bsz * D * T * 2;   // 4 MiB
    f16* ret16   = (f16*)ws;  ws += (size_t)M * D * 2;         // 4 MiB
    f16* x2_16   = (f16*)ws;  ws += (size_t)M * V * 2;         // 32 MiB (residual stream, f16)
    float* rowss = (float*)ws; ws += (size_t)M * 4;            // 32 KiB (sum x2^2 per row)
    f16* h16     = q16;  // reuse q16+k16 region (8 MiB) after attention

    float* out = (float*)d_out;

    // 1. prep: weight conversion + rmsnorm(x) + rowss zeroing, one launch
    prep_kernel<<<dim3(12288), 256, 0, stream>>>(Wq, Wk, Wv, Wo, Wdown, Wup,
                                                 Wqkv16, x, xn16, rowss);

    // 2. QKV GEMM (fused, N=768), K=2048: BK=64 kernel, 384 blocks (measured best)
    {
        GemmEpi e = {};
        e.out_q = q16; e.out_k = k16; e.out_vT = vT16;
        gemm_nt_k64<0><<<dim3(M / 128, 768 / 128), 256, 0, stream>>>(xn16, Wqkv16, V, e);
    }

    // 3. fused decay-attention -> ret16
    attn_kernel<<<dim3(T / 32, Bsz), 256, 0, stream>>>(q16, k16, vT16, ret16, decay_logit);

    // 4. Wo GEMM + residual + row-ss: x2 = x + qs*qos*(ret @ Wo^T), rowss += x2^2
    {
        GemmEpi e = {};
        e.residf = x; e.outh = x2_16; e.sA = q_scale; e.sB = q_out_scale;
        e.rowss = rowss;
        gemm_nt<1><<<dim3(M / 128, V / 128), 256, 0, stream>>>(ret16, Wo16, D, e);
    }

    // 5. Wdown GEMM on RAW x2 + per-row rms scale + bias + exact gelu -> h16
    {
        GemmEpi e = {};
        e.out_h = h16; e.bias = t_bias; e.rowss = rowss;
        gemm_nt_k64<2><<<dim3(M / 128, R / 128), 256, 0, stream>>>(x2_16, Wdown16, V, e);
    }

    // 6. Wup GEMM + residual: out (fp32) = x2 + ts*tos*(h @ Wup^T)  (K=512)
    {
        GemmEpi e = {};
        e.residh = x2_16; e.outf = out; e.sA = t_scale; e.sB = t_out_scale;
        gemm_nt<3><<<dim3(M / 128, V / 128), 256, 0, stream>>>(h16, Wup16, R, e);
    }
}